// Round 12
// baseline (203.028 us; speedup 1.0000x reference)
//
#include <hip/hip_runtime.h>
#include <hip/hip_bf16.h>
#include <math.h>

#define B_    16
#define N_    1000
#define BN_   16000
#define T_    16
#define FO    16
#define H_    128
#define G3    384       // 3*H
#define HEADS 5
#define HC    640       // heads*H
#define E_    4000
#define EG    64000     // B*E
#define ETOT  80000     // EG + BN self loops
#define P_    8
#define A_    8
#define NEG_SLOPE 0.2f
#define L2E   1.44269504f

typedef __attribute__((ext_vector_type(8))) short bf16x8;
typedef __attribute__((ext_vector_type(4))) float f32x4;

__device__ __forceinline__ float bf2f(unsigned short u){ return __uint_as_float(((unsigned)u)<<16); }
__device__ __forceinline__ unsigned short f2bf(float x){
    unsigned u = __float_as_uint(x);
    unsigned r = (u + 0x7FFFu + ((u>>16)&1u)) >> 16;
    return (unsigned short)r;
}
__device__ __forceinline__ unsigned cvtpk(float lo, float hi){
    unsigned r;
    asm volatile("v_cvt_pk_bf16_f32 %0, %1, %2" : "=v"(r) : "v"(lo), "v"(hi));
    return r;
}
__device__ __forceinline__ float rcpf(float x){ return __builtin_amdgcn_rcpf(x); }

// ---------- K1: weight prep + init (blocks 0..639) | conv1 (blocks 640..1151) ----------
// GRU weights are pre-scaled: r,z rows x log2e; n rows x 2*log2e (exp2-direct gates).
__global__ __launch_bounds__(256) void k_prep_c1(
        const float* __restrict__ Wih, const float* __restrict__ Whh,
        const float* __restrict__ Wl, const float* __restrict__ Wr,
        const float* __restrict__ Wn, const float* __restrict__ bn,
        unsigned short* __restrict__ Wihb, unsigned short* __restrict__ Whhb,
        unsigned short* __restrict__ WTb, unsigned short* __restrict__ WnTb,
        float* __restrict__ segsum, float* __restrict__ node_out,
        float* __restrict__ tacc,
        const float* __restrict__ im, const float* __restrict__ w1,
        const float* __restrict__ b1, float* __restrict__ c1out){
    __shared__ float sW[32*4*9];
    int t = threadIdx.x;
    if(blockIdx.x < 640){
        int i = blockIdx.x*256 + t;
        if(i < G3*H_){
            float sc = ((i >> 7) < 256) ? L2E : 2.0f*L2E;
            Wihb[i] = f2bf(Wih[i]*sc); Whhb[i] = f2bf(Whh[i]*sc);
        }
        if(i < 2*HC*H_){
            int c = i >> 7, k = i & 127;
            float v = (c < HC) ? Wl[(size_t)k*HC + c] : Wr[(size_t)k*HC + (c-HC)];
            WTb[i] = f2bf(v);
        }
        if(i < H_*32){
            int c = i >> 5, k = i & 31;
            WnTb[i] = (k < FO) ? f2bf(Wn[k*H_ + c])
                     : (k == FO ? f2bf(bn[c]) : (unsigned short)0);
        }
        if(i < BN_*HEADS) segsum[i] = 0.0f;
        if(i < B_*HC) node_out[i] = 0.0f;
        if(i < B_*H_) tacc[i] = 0.0f;
    } else {
        for(int i=t;i<32*4*9;i+=256) sW[i]=w1[i];
        __syncthreads();
        int idx = (blockIdx.x-640)*256 + t;
        int ox = idx & 15, oy = (idx>>4)&15, oc = (idx>>8)&31, b = idx>>13;
        float acc = b1[oc];
        for(int ic=0;ic<4;ic++){
            const float* ip = &im[(size_t)((b*4+ic)*32)*32];
            const float* wp = &sW[(oc*4+ic)*9];
            #pragma unroll
            for(int ky=0;ky<3;ky++){
                int iy = oy*2+ky; if(iy>=32) continue;
                #pragma unroll
                for(int kx=0;kx<3;kx++){
                    int ix = ox*2+kx; if(ix>=32) continue;
                    acc = fmaf(ip[iy*32+ix], wp[ky*3+kx], acc);
                }
            }
        }
        c1out[idx] = fmaxf(acc, 0.f);
    }
}

// ============ K2: fused obs-MLP + gx + GRU, 64 nodes/block, 8 waves ============
// Pairwise group processing: 12 MFMAs/kt across 8 independent accumulator chains
// -> MFMA latency hidden by issue. Gates use exp2-direct (weights pre-scaled).
__global__ __launch_bounds__(512,2) void k_gruf(const float* __restrict__ obs,
        const unsigned short* __restrict__ WnTb,
        const unsigned short* __restrict__ Wihb, const float* __restrict__ bih,
        const unsigned short* __restrict__ Whhb, const float* __restrict__ bhh,
        unsigned short* __restrict__ hout){
    __shared__ unsigned short sX[2*8192];   // [buf][grp(4)][16 nodes][128], swizzled
    __shared__ unsigned short sH[2*8192];
    int t = threadIdx.x;
    int w = t>>6, lane = t&63, lq = lane>>4, lm = lane&15;

    bf16x8 wfi[3][4], wfh[3][4];
    #pragma unroll
    for(int i=0;i<3;i++){
        int row = (8*i + w)*16 + lm;
        #pragma unroll
        for(int kt=0;kt<4;kt++){
            wfi[i][kt] = *(const bf16x8*)&Wihb[row*H_ + kt*32 + lq*8];
            wfh[i][kt] = *(const bf16x8*)&Whhb[row*H_ + kt*32 + lq*8];
        }
    }
    bf16x8 wfn = *(const bf16x8*)&WnTb[(w*16+lm)*32 + lq*8];
    int cb = w*16 + lq*4;
    f32x4 b_r, b_z, bxn, bhn;
    { f32x4 t1=*(const f32x4*)&bih[cb],     t2=*(const f32x4*)&bhh[cb];     b_r=(t1+t2)*L2E; }
    { f32x4 t1=*(const f32x4*)&bih[128+cb], t2=*(const f32x4*)&bhh[128+cb]; b_z=(t1+t2)*L2E; }
    bxn = *(const f32x4*)&bih[256+cb] * (2.0f*L2E);
    bhn = *(const f32x4*)&bhh[256+cb] * (2.0f*L2E);

    int rd[4];
    #pragma unroll
    for(int kt=0;kt<4;kt++) rd[kt] = lm*128 + (((4*kt+lq)^(lm&7))<<3);
    const int wrt = lm*128 + (((2*w + (lq>>1))^(lm&7))<<3) + ((lq&1)<<2);

    int nodeBase = blockIdx.x*64;
    const float* obp0 = &obs[(size_t)(nodeBase + lm)*256 + lq*8];

    for(int i=t;i<4096;i+=512) ((unsigned*)sH)[i] = 0u;   // zero sH buf 0 (16KB)
    float ho[4][4] = {{0.f,0.f,0.f,0.f},{0.f,0.f,0.f,0.f},
                      {0.f,0.f,0.f,0.f},{0.f,0.f,0.f,0.f}};

    // prologue: X(0) for all 4 groups
    #pragma unroll
    for(int g=0; g<4; g++){
        bf16x8 ob = (bf16x8){0,0,0,0,0,0,0,0};
        if(lq < 2){
            const float* q = obp0 + (size_t)g*16*256;
            float4 a = *(const float4*)(q), b = *(const float4*)(q+4);
            union { uint4 u; bf16x8 v; } cv;
            cv.u = make_uint4(cvtpk(a.x,a.y), cvtpk(a.z,a.w),
                              cvtpk(b.x,b.y), cvtpk(b.z,b.w));
            ob = cv.v;
        } else if(lq == 2){
            ob[0] = (short)0x3F80;          // k==16 -> bias row of WnT
        }
        f32x4 xa = (f32x4){0.f,0.f,0.f,0.f};
        xa = __builtin_amdgcn_mfma_f32_16x16x32_bf16(wfn, ob, xa, 0,0,0);
        unsigned u0 = cvtpk(fmaxf(xa[0],0.f), fmaxf(xa[1],0.f));
        unsigned u1 = cvtpk(fmaxf(xa[2],0.f), fmaxf(xa[3],0.f));
        *(uint2*)&sX[g*2048 + wrt] = make_uint2(u0,u1);
    }
    __syncthreads();

    int p = 0;
    #pragma unroll 1
    for(int s=0; s<T_; s++){
        #pragma unroll
        for(int pr=0; pr<2; pr++){
            int g0 = pr*2, g1 = pr*2+1;
            int base0 = p*8192 + g0*2048;
            int base1 = p*8192 + g1*2048;
            bf16x8 xb0[4], hb0[4], xb1[4], hb1[4];
            #pragma unroll
            for(int kt=0;kt<4;kt++){
                xb0[kt] = *(const bf16x8*)&sX[base0 + rd[kt]];
                hb0[kt] = *(const bf16x8*)&sH[base0 + rd[kt]];
                xb1[kt] = *(const bf16x8*)&sX[base1 + rd[kt]];
                hb1[kt] = *(const bf16x8*)&sH[base1 + rd[kt]];
            }
            f32x4 ar0=b_r, az0=b_z, ax0=bxn, ah0=bhn;
            f32x4 ar1=b_r, az1=b_z, ax1=bxn, ah1=bhn;
            #pragma unroll
            for(int kt=0;kt<4;kt++){
                ar0 = __builtin_amdgcn_mfma_f32_16x16x32_bf16(wfi[0][kt], xb0[kt], ar0, 0,0,0);
                ar1 = __builtin_amdgcn_mfma_f32_16x16x32_bf16(wfi[0][kt], xb1[kt], ar1, 0,0,0);
                az0 = __builtin_amdgcn_mfma_f32_16x16x32_bf16(wfi[1][kt], xb0[kt], az0, 0,0,0);
                az1 = __builtin_amdgcn_mfma_f32_16x16x32_bf16(wfi[1][kt], xb1[kt], az1, 0,0,0);
                ax0 = __builtin_amdgcn_mfma_f32_16x16x32_bf16(wfi[2][kt], xb0[kt], ax0, 0,0,0);
                ax1 = __builtin_amdgcn_mfma_f32_16x16x32_bf16(wfi[2][kt], xb1[kt], ax1, 0,0,0);
                ar0 = __builtin_amdgcn_mfma_f32_16x16x32_bf16(wfh[0][kt], hb0[kt], ar0, 0,0,0);
                ar1 = __builtin_amdgcn_mfma_f32_16x16x32_bf16(wfh[0][kt], hb1[kt], ar1, 0,0,0);
                az0 = __builtin_amdgcn_mfma_f32_16x16x32_bf16(wfh[1][kt], hb0[kt], az0, 0,0,0);
                az1 = __builtin_amdgcn_mfma_f32_16x16x32_bf16(wfh[1][kt], hb1[kt], az1, 0,0,0);
                ah0 = __builtin_amdgcn_mfma_f32_16x16x32_bf16(wfh[2][kt], hb0[kt], ah0, 0,0,0);
                ah1 = __builtin_amdgcn_mfma_f32_16x16x32_bf16(wfh[2][kt], hb1[kt], ah1, 0,0,0);
            }
            #pragma unroll
            for(int v=0;v<4;v++){
                float r  = rcpf(1.f + exp2f(-ar0[v]));
                float z  = rcpf(1.f + exp2f(-az0[v]));
                float xn = fmaf(r, ah0[v], ax0[v]);
                float nn = fmaf(2.f, rcpf(1.f + exp2f(-xn)), -1.f);
                ho[g0][v] = nn + z*(ho[g0][v] - nn);
            }
            #pragma unroll
            for(int v=0;v<4;v++){
                float r  = rcpf(1.f + exp2f(-ar1[v]));
                float z  = rcpf(1.f + exp2f(-az1[v]));
                float xn = fmaf(r, ah1[v], ax1[v]);
                float nn = fmaf(2.f, rcpf(1.f + exp2f(-xn)), -1.f);
                ho[g1][v] = nn + z*(ho[g1][v] - nn);
            }
            *(uint2*)&sH[(p^1)*8192 + g0*2048 + wrt] =
                make_uint2(cvtpk(ho[g0][0], ho[g0][1]), cvtpk(ho[g0][2], ho[g0][3]));
            *(uint2*)&sH[(p^1)*8192 + g1*2048 + wrt] =
                make_uint2(cvtpk(ho[g1][0], ho[g1][1]), cvtpk(ho[g1][2], ho[g1][3]));
            // X(s+1) for this pair's groups
            if(s < T_-1){
                #pragma unroll
                for(int gi=0; gi<2; gi++){
                    int g = pr*2 + gi;
                    bf16x8 ob = (bf16x8){0,0,0,0,0,0,0,0};
                    if(lq < 2){
                        const float* q = obp0 + (size_t)g*16*256 + (s+1)*16;
                        float4 a = *(const float4*)(q), b = *(const float4*)(q+4);
                        union { uint4 u; bf16x8 v; } cv;
                        cv.u = make_uint4(cvtpk(a.x,a.y), cvtpk(a.z,a.w),
                                          cvtpk(b.x,b.y), cvtpk(b.z,b.w));
                        ob = cv.v;
                    } else if(lq == 2){
                        ob[0] = (short)0x3F80;
                    }
                    f32x4 xa = (f32x4){0.f,0.f,0.f,0.f};
                    xa = __builtin_amdgcn_mfma_f32_16x16x32_bf16(wfn, ob, xa, 0,0,0);
                    unsigned u0 = cvtpk(fmaxf(xa[0],0.f), fmaxf(xa[1],0.f));
                    unsigned u1 = cvtpk(fmaxf(xa[2],0.f), fmaxf(xa[3],0.f));
                    *(uint2*)&sX[(p^1)*8192 + g*2048 + wrt] = make_uint2(u0,u1);
                }
            }
        }
        __syncthreads();
        p ^= 1;
    }
    #pragma unroll
    for(int g=0; g<4; g++){
        unsigned u0 = cvtpk(ho[g][0], ho[g][1]);
        unsigned u1 = cvtpk(ho[g][2], ho[g][3]);
        *(uint2*)&hout[(size_t)(nodeBase + g*16 + lm)*H_ + cb] = make_uint2(u0,u1);
    }
}

// ---------- K3: xl|xr GEMM (blocks 0..624) | conv2 (blocks 625..880) ----------
__global__ __launch_bounds__(256) void k_xlxr_c2(const unsigned short* __restrict__ hb16,
        const unsigned short* __restrict__ WTb,
        unsigned short* __restrict__ xl, unsigned short* __restrict__ xr,
        const float* __restrict__ c1, const float* __restrict__ w2,
        const float* __restrict__ b2, float* __restrict__ c2out){
    int t = threadIdx.x;
    if(blockIdx.x < 625){
        int w = t>>6, lane = t&63, lq = lane>>4, lm = lane&15;
        int nb = blockIdx.x / 5, cgrp = blockIdx.x % 5;
        int nblk = nb*128;
        int ct0 = cgrp*16 + w*4;
        bf16x8 wf[4][4];
        #pragma unroll
        for(int i=0;i<4;i++){
            int row = (ct0+i)*16 + lm;
            #pragma unroll
            for(int kt=0;kt<4;kt++)
                wf[i][kt] = *(const bf16x8*)&WTb[(size_t)row*H_ + kt*32 + lq*8];
        }
        for(int g=0; g<8; g++){
            int node = nblk + g*16 + lm;
            bf16x8 hb[4];
            #pragma unroll
            for(int kt=0;kt<4;kt++)
                hb[kt] = *(const bf16x8*)&hb16[(size_t)node*H_ + kt*32 + lq*8];
            f32x4 acc[4];
            #pragma unroll
            for(int i=0;i<4;i++) acc[i] = (f32x4){0.f,0.f,0.f,0.f};
            #pragma unroll
            for(int kt=0;kt<4;kt++){
                #pragma unroll
                for(int i=0;i<4;i++)
                    acc[i] = __builtin_amdgcn_mfma_f32_16x16x32_bf16(wf[i][kt], hb[kt], acc[i], 0,0,0);
            }
            #pragma unroll
            for(int i=0;i<4;i++){
                int col = (ct0+i)*16 + lq*4;
                ushort4 o;
                o.x=f2bf(acc[i][0]); o.y=f2bf(acc[i][1]); o.z=f2bf(acc[i][2]); o.w=f2bf(acc[i][3]);
                if(col < HC) *(ushort4*)&xl[(size_t)node*HC + col] = o;
                else         *(ushort4*)&xr[(size_t)node*HC + (col-HC)] = o;
            }
        }
    } else {
        int idx = (blockIdx.x-625)*256 + t;
        int ox = idx & 7, oy = (idx>>3)&7, oc = (idx>>6)&63, b = idx>>12;
        float acc = b2[oc];
        for(int ic=0;ic<32;ic++){
            const float* ip = &c1[(size_t)((b*32+ic)*16)*16];
            const float* wp = &w2[(oc*32+ic)*9];
            #pragma unroll
            for(int ky=0;ky<3;ky++){
                int iy = oy*2+ky; if(iy>=16) continue;
                #pragma unroll
                for(int kx=0;kx<3;kx++){
                    int ix = ox*2+kx; if(ix>=16) continue;
                    acc = fmaf(ip[iy*16+ix], wp[ky*3+kx], acc);
                }
            }
        }
        c2out[idx] = fmaxf(acc, 0.f);
    }
}

// ---------------- edge src/dst helper ----------------
__device__ __forceinline__ void edge_sd(int e, const int* __restrict__ edges, int* src, int* dst){
    if(e < EG){
        int b = e / E_, j = e - b*E_;
        *src = edges[(b*2+0)*E_ + j] + b*N_;
        *dst = edges[(b*2+1)*E_ + j] + b*N_;
    } else { *src = *dst = e - EG; }
}

// ---------- K4: logits+exp+segsum, XCD-swizzled (blocks 0..4999) | temb (5000..5511) ----
__global__ __launch_bounds__(256) void k_logits_tb(const unsigned short* __restrict__ xl,
        const unsigned short* __restrict__ xr, const int* __restrict__ edges,
        const float* __restrict__ atta, float* __restrict__ pbuf,
        float* __restrict__ segsum,
        const float* __restrict__ c2, const float* __restrict__ Wc,
        float* __restrict__ tacc){
    __shared__ float sC[128];
    int t = threadIdx.x;
    if(blockIdx.x < 5000){
        int lb = (blockIdx.x & 7)*625 + (blockIdx.x >> 3);
        int lane = t & 63, w = t >> 6;
        float am[8], a4[8];
        #pragma unroll
        for(int j=0;j<8;j++) am[j] = atta[lane*8+j];
        #pragma unroll
        for(int j=0;j<8;j++) a4[j] = (lane<16) ? atta[512+lane*8+j] : 0.f;

        int e0 = lb*16 + w*4;
        int srcs[4], dsts[4];
        #pragma unroll
        for(int i=0;i<4;i++) edge_sd(e0+i, edges, &srcs[i], &dsts[i]);
        #pragma unroll
        for(int i=0;i<4;i++){
            const unsigned short* xls = &xl[(size_t)srcs[i]*HC];
            const unsigned short* xrd = &xr[(size_t)dsts[i]*HC];
            uint4 ul = *(const uint4*)&xls[lane*8];
            uint4 ur = *(const uint4*)&xrd[lane*8];
            uint4 tl = make_uint4(0,0,0,0), tr = make_uint4(0,0,0,0);
            if(lane < 16){
                tl = *(const uint4*)&xls[512+lane*8];
                tr = *(const uint4*)&xrd[512+lane*8];
            }
            float pm = 0.f, p4 = 0.f;
            {
                unsigned pl[4] = {ul.x,ul.y,ul.z,ul.w};
                unsigned pr[4] = {ur.x,ur.y,ur.z,ur.w};
                #pragma unroll
                for(int q=0;q<4;q++){
                    float s0 = bf2f((unsigned short)(pl[q]&0xFFFFu)) + bf2f((unsigned short)(pr[q]&0xFFFFu));
                    float s1 = bf2f((unsigned short)(pl[q]>>16))     + bf2f((unsigned short)(pr[q]>>16));
                    s0 = s0 > 0.f ? s0 : NEG_SLOPE*s0;
                    s1 = s1 > 0.f ? s1 : NEG_SLOPE*s1;
                    pm = fmaf(s0, am[2*q],   pm);
                    pm = fmaf(s1, am[2*q+1], pm);
                }
            }
            {
                unsigned ql[4] = {tl.x,tl.y,tl.z,tl.w};
                unsigned qr[4] = {tr.x,tr.y,tr.z,tr.w};
                #pragma unroll
                for(int q=0;q<4;q++){
                    float s0 = bf2f((unsigned short)(ql[q]&0xFFFFu)) + bf2f((unsigned short)(qr[q]&0xFFFFu));
                    float s1 = bf2f((unsigned short)(ql[q]>>16))     + bf2f((unsigned short)(qr[q]>>16));
                    s0 = s0 > 0.f ? s0 : NEG_SLOPE*s0;
                    s1 = s1 > 0.f ? s1 : NEG_SLOPE*s1;
                    p4 = fmaf(s0, a4[2*q],   p4);
                    p4 = fmaf(s1, a4[2*q+1], p4);
                }
            }
            #pragma unroll
            for(int off=1; off<16; off<<=1){
                pm += __shfl_xor(pm, off);
                p4 += __shfl_xor(p4, off);
            }
            if((lane & 15) == 0){
                int hh = lane >> 4;
                float p = __expf(pm);
                pbuf[(size_t)(e0+i)*HEADS + hh] = p;
                atomicAdd(&segsum[dsts[i]*HEADS + hh], p);
            }
            if(lane == 8){
                float p = __expf(p4);
                pbuf[(size_t)(e0+i)*HEADS + 4] = p;
                atomicAdd(&segsum[dsts[i]*HEADS + 4], p);
            }
        }
    } else {
        int bb = blockIdx.x - 5000;
        int b = bb >> 5, ks = bb & 31;
        int k0 = ks*128;
        if(t < 128) sC[t] = c2[(size_t)b*4096 + k0 + t];
        __syncthreads();
        int j = t & 127, sub = t >> 7;
        const float* wp = &Wc[(size_t)(k0 + sub*64)*H_ + j];
        const float* cp = &sC[sub*64];
        float a0=0.f, a1=0.f, a2=0.f, a3=0.f;
        #pragma unroll
        for(int kk=0; kk<64; kk+=4){
            a0 = fmaf(cp[kk+0], wp[(size_t)(kk+0)*H_], a0);
            a1 = fmaf(cp[kk+1], wp[(size_t)(kk+1)*H_], a1);
            a2 = fmaf(cp[kk+2], wp[(size_t)(kk+2)*H_], a2);
            a3 = fmaf(cp[kk+3], wp[(size_t)(kk+3)*H_], a3);
        }
        atomicAdd(&tacc[b*H_+j], (a0+a1)+(a2+a3));
    }
}

// ---------------- K5: alpha = p/segsum + wave-cooperative ego accumulation ----------
__global__ void k_alpha(const float* __restrict__ pbuf, const float* __restrict__ segsum,
                        const int* __restrict__ edges, const unsigned short* __restrict__ xl,
                        float* __restrict__ out_alpha, float* __restrict__ node_out){
    int idx = blockIdx.x*256 + threadIdx.x;
    int lane = threadIdx.x & 63;
    bool valid = idx < ETOT*HEADS;
    int e = 0, hh = 0, src = 0, dst = 0;
    float a = 0.f;
    bool ego = false;
    if(valid){
        e = idx / HEADS; hh = idx - e*HEADS;
        edge_sd(e, edges, &src, &dst);
        a = pbuf[idx] / segsum[dst*HEADS + hh];
        out_alpha[idx] = a;
        ego = (dst % N_) == 0;
    }
    unsigned long long m = __ballot(ego);
    while(m){
        int l = __ffsll((unsigned long long)m) - 1;
        m &= (m - 1);
        float aa = __shfl(a, l);
        int ss = __shfl(src, l), dd = __shfl(dst, l), hq = __shfl(hh, l);
        int b = dd / N_;
        unsigned u = *(const unsigned*)&xl[(size_t)ss*HC + hq*H_ + lane*2];
        float* no = &node_out[b*HC + hq*H_ + lane*2];
        atomicAdd(no,     aa * bf2f((unsigned short)(u & 0xFFFFu)));
        atomicAdd(no + 1, aa * bf2f((unsigned short)(u >> 16)));
    }
}

// ---------------- K6: head ----------------
__global__ __launch_bounds__(256) void k_head(const float* __restrict__ node_out,
        const float* __restrict__ gat_bias, const float* __restrict__ tacc,
        const float* __restrict__ bc, const float* __restrict__ phase,
        const float* __restrict__ Wp, const float* __restrict__ bp,
        const float* __restrict__ Wh, const float* __restrict__ bh,
        const float* __restrict__ Wo, const float* __restrict__ bo,
        const float* __restrict__ Wa, const float* __restrict__ ba,
        float* __restrict__ out){
    __shared__ float sF[16][268];
    __shared__ float sHid[16][132];
    int t = threadIdx.x;
    for(int i=t;i<B_*H_;i+=256){
        int b=i>>7, c=i&127;
        float s=0.f;
        #pragma unroll
        for(int hh=0;hh<HEADS;hh++) s += node_out[b*HC + hh*H_ + c];
        sF[b][c] = s*(1.0f/HEADS) + gat_bias[c];
    }
    for(int i=t;i<B_*H_;i+=256){
        int b=i>>7, c=i&127;
        sF[b][128+c] = fmaxf(tacc[i] + bc[c], 0.f);
    }
    if(t < B_*P_){
        int b=t>>3, p=t&7;
        float s=bp[p];
        #pragma unroll
        for(int q=0;q<P_;q++) s = fmaf(phase[b*P_+q], Wp[q*P_+p], s);
        sF[b][256+p] = fmaxf(s, 0.f);
    }
    __syncthreads();
    for(int i=t;i<B_*H_;i+=256){
        int b=i>>7, j=i&127;
        float s=bh[j];
        for(int k=0;k<2*H_+P_;k++) s = fmaf(sF[b][k], Wh[k*H_+j], s);
        sHid[b][j]=fmaxf(s,0.f);
    }
    __syncthreads();
    if(t < B_*A_){
        int b=t>>3, a=t&7;
        float v=bo[0], ad=ba[a];
        for(int k=0;k<H_;k++){ float hv=sHid[b][k]; v = fmaf(hv,Wo[k],v); ad = fmaf(hv,Wa[k*A_+a],ad); }
        float m = ad;
        m += __shfl_xor(m,1); m += __shfl_xor(m,2); m += __shfl_xor(m,4);
        m *= 0.125f;
        out[b*A_+a] = v + ad - m;
    }
}

extern "C" void kernel_launch(void* const* d_in, const int* in_sizes, int n_in,
                              void* d_out, int out_size, void* d_ws, size_t ws_size,
                              hipStream_t stream) {
    (void)in_sizes; (void)n_in; (void)out_size; (void)ws_size;
    const float* obs      = (const float*)d_in[0];
    const float* phase    = (const float*)d_in[1];
    const float* obs_map  = (const float*)d_in[2];
    const int*   edges    = (const int*)  d_in[3];
    const float* W_nbrs   = (const float*)d_in[5];
    const float* b_nbrs   = (const float*)d_in[6];
    const float* W_ih     = (const float*)d_in[7];
    const float* W_hh     = (const float*)d_in[8];
    const float* b_ih     = (const float*)d_in[9];
    const float* b_hh     = (const float*)d_in[10];
    const float* Wl       = (const float*)d_in[11];
    const float* Wr       = (const float*)d_in[12];
    const float* att_a    = (const float*)d_in[13];
    const float* gat_bias = (const float*)d_in[14];
    const float* conv1_w  = (const float*)d_in[15];
    const float* conv1_b  = (const float*)d_in[16];
    const float* conv2_w  = (const float*)d_in[17];
    const float* conv2_b  = (const float*)d_in[18];
    const float* Wc       = (const float*)d_in[19];
    const float* bc       = (const float*)d_in[20];
    const float* Wp       = (const float*)d_in[21];
    const float* bp       = (const float*)d_in[22];
    const float* Wh       = (const float*)d_in[23];
    const float* bh       = (const float*)d_in[24];
    const float* Wo       = (const float*)d_in[25];
    const float* bo       = (const float*)d_in[26];
    const float* Wa       = (const float*)d_in[27];
    const float* ba       = (const float*)d_in[28];

    float* out = (float*)d_out;                 // [0,128): out ; [128,400128): alpha
    float* w   = (float*)d_ws;

    size_t off = 0;
    unsigned short* hbuf = (unsigned short*)(w + off); off += (size_t)BN_*H_/2;
    unsigned short* xl   = (unsigned short*)(w + off); off += (size_t)BN_*HC/2;
    unsigned short* xr   = (unsigned short*)(w + off); off += (size_t)BN_*HC/2;
    float* pbuf   = w + off; off += (size_t)ETOT*HEADS;
    float* segsum = w + off; off += (size_t)BN_*HEADS;
    float* nodeo  = w + off; off += (size_t)B_*HC;
    float* c1     = w + off; off += (size_t)16*32*16*16;
    float* c2     = w + off; off += (size_t)16*64*8*8;
    float* tacc   = w + off; off += (size_t)B_*H_;
    unsigned short* Wihb = (unsigned short*)(w + off); off += (size_t)H_*G3/2;
    unsigned short* Whhb = (unsigned short*)(w + off); off += (size_t)H_*G3/2;
    unsigned short* WTb  = (unsigned short*)(w + off); off += (size_t)2*HC*H_/2;
    unsigned short* WnTb = (unsigned short*)(w + off); off += (size_t)H_*32/2;

    k_prep_c1<<<640 + 512, 256, 0, stream>>>(W_ih, W_hh, Wl, Wr, W_nbrs, b_nbrs,
                                             Wihb, Whhb, WTb, WnTb,
                                             segsum, nodeo, tacc,
                                             obs_map, conv1_w, conv1_b, c1);

    k_gruf<<<BN_/64, 512, 0, stream>>>(obs, WnTb, Wihb, b_ih, Whhb, b_hh, hbuf);

    k_xlxr_c2<<<625 + 256, 256, 0, stream>>>(hbuf, WTb, xl, xr,
                                             c1, conv2_w, conv2_b, c2);

    k_logits_tb<<<5000 + 512, 256, 0, stream>>>(xl, xr, edges, att_a, pbuf, segsum,
                                                c2, Wc, tacc);

    k_alpha<<<(ETOT*HEADS+255)/256, 256, 0, stream>>>(pbuf, segsum, edges, xl, out+128, nodeo);

    k_head<<<1, 256, 0, stream>>>(nodeo, gat_bias, tacc, bc, phase,
                                  Wp, bp, Wh, bh, Wo, bo, Wa, ba, out);
}

// Round 13
// 201.903 us; speedup vs baseline: 1.0056x; 1.0056x over previous
//
#include <hip/hip_runtime.h>
#include <hip/hip_bf16.h>
#include <math.h>

#define B_    16
#define N_    1000
#define BN_   16000
#define T_    16
#define FO    16
#define H_    128
#define G3    384       // 3*H
#define HEADS 5
#define HC    640       // heads*H
#define E_    4000
#define EG    64000     // B*E
#define ETOT  80000     // EG + BN self loops
#define P_    8
#define A_    8
#define NEG_SLOPE 0.2f
#define L2E   1.44269504f

typedef __attribute__((ext_vector_type(8))) short bf16x8;
typedef __attribute__((ext_vector_type(4))) float f32x4;

__device__ __forceinline__ float bf2f(unsigned short u){ return __uint_as_float(((unsigned)u)<<16); }
__device__ __forceinline__ unsigned short f2bf(float x){
    unsigned u = __float_as_uint(x);
    unsigned r = (u + 0x7FFFu + ((u>>16)&1u)) >> 16;
    return (unsigned short)r;
}
__device__ __forceinline__ unsigned cvtpk(float lo, float hi){
    unsigned r;
    asm volatile("v_cvt_pk_bf16_f32 %0, %1, %2" : "=v"(r) : "v"(lo), "v"(hi));
    return r;
}
__device__ __forceinline__ float rcpf(float x){ return __builtin_amdgcn_rcpf(x); }

// ---------- K1: weight prep + init (blocks 0..639) | conv1 (blocks 640..1151) ----------
// GRU weights pre-scaled: r,z rows x log2e; n rows x 2*log2e (exp2-direct gates).
__global__ __launch_bounds__(256) void k_prep_c1(
        const float* __restrict__ Wih, const float* __restrict__ Whh,
        const float* __restrict__ Wl, const float* __restrict__ Wr,
        const float* __restrict__ Wn, const float* __restrict__ bn,
        unsigned short* __restrict__ Wihb, unsigned short* __restrict__ Whhb,
        unsigned short* __restrict__ WTb, unsigned short* __restrict__ WnTb,
        float* __restrict__ segsum, float* __restrict__ node_out,
        float* __restrict__ tacc,
        const float* __restrict__ im, const float* __restrict__ w1,
        const float* __restrict__ b1, float* __restrict__ c1out){
    __shared__ float sW[32*4*9];
    int t = threadIdx.x;
    if(blockIdx.x < 640){
        int i = blockIdx.x*256 + t;
        if(i < G3*H_){
            float sc = ((i >> 7) < 256) ? L2E : 2.0f*L2E;
            Wihb[i] = f2bf(Wih[i]*sc); Whhb[i] = f2bf(Whh[i]*sc);
        }
        if(i < 2*HC*H_){
            int c = i >> 7, k = i & 127;
            float v = (c < HC) ? Wl[(size_t)k*HC + c] : Wr[(size_t)k*HC + (c-HC)];
            WTb[i] = f2bf(v);
        }
        if(i < H_*32){
            int c = i >> 5, k = i & 31;
            WnTb[i] = (k < FO) ? f2bf(Wn[k*H_ + c])
                     : (k == FO ? f2bf(bn[c]) : (unsigned short)0);
        }
        if(i < BN_*HEADS) segsum[i] = 0.0f;
        if(i < B_*HC) node_out[i] = 0.0f;
        if(i < B_*H_) tacc[i] = 0.0f;
    } else {
        for(int i=t;i<32*4*9;i+=256) sW[i]=w1[i];
        __syncthreads();
        int idx = (blockIdx.x-640)*256 + t;
        int ox = idx & 15, oy = (idx>>4)&15, oc = (idx>>8)&31, b = idx>>13;
        float acc = b1[oc];
        for(int ic=0;ic<4;ic++){
            const float* ip = &im[(size_t)((b*4+ic)*32)*32];
            const float* wp = &sW[(oc*4+ic)*9];
            #pragma unroll
            for(int ky=0;ky<3;ky++){
                int iy = oy*2+ky; if(iy>=32) continue;
                #pragma unroll
                for(int kx=0;kx<3;kx++){
                    int ix = ox*2+kx; if(ix>=32) continue;
                    acc = fmaf(ip[iy*32+ix], wp[ky*3+kx], acc);
                }
            }
        }
        c1out[idx] = fmaxf(acc, 0.f);
    }
}

// ============ K2: fused obs-MLP + gx + GRU, 64 nodes/block, 8 waves ============
// r11 structure (serial groups, bias-in-C chaining) + exp2-direct gates.
__global__ __launch_bounds__(512,2) void k_gruf(const float* __restrict__ obs,
        const unsigned short* __restrict__ WnTb,
        const unsigned short* __restrict__ Wihb, const float* __restrict__ bih,
        const unsigned short* __restrict__ Whhb, const float* __restrict__ bhh,
        unsigned short* __restrict__ hout){
    __shared__ unsigned short sX[2*8192];   // [buf][grp(4)][16 nodes][128], swizzled
    __shared__ unsigned short sH[2*8192];
    int t = threadIdx.x;
    int w = t>>6, lane = t&63, lq = lane>>4, lm = lane&15;

    bf16x8 wfi[3][4], wfh[3][4];
    #pragma unroll
    for(int i=0;i<3;i++){
        int row = (8*i + w)*16 + lm;
        #pragma unroll
        for(int kt=0;kt<4;kt++){
            wfi[i][kt] = *(const bf16x8*)&Wihb[row*H_ + kt*32 + lq*8];
            wfh[i][kt] = *(const bf16x8*)&Whhb[row*H_ + kt*32 + lq*8];
        }
    }
    bf16x8 wfn = *(const bf16x8*)&WnTb[(w*16+lm)*32 + lq*8];
    int cb = w*16 + lq*4;
    f32x4 b_r, b_z, bxn, bhn;
    { f32x4 t1=*(const f32x4*)&bih[cb],     t2=*(const f32x4*)&bhh[cb];     b_r=(t1+t2)*L2E; }
    { f32x4 t1=*(const f32x4*)&bih[128+cb], t2=*(const f32x4*)&bhh[128+cb]; b_z=(t1+t2)*L2E; }
    bxn = *(const f32x4*)&bih[256+cb] * (2.0f*L2E);
    bhn = *(const f32x4*)&bhh[256+cb] * (2.0f*L2E);

    int rd[4];
    #pragma unroll
    for(int kt=0;kt<4;kt++) rd[kt] = lm*128 + (((4*kt+lq)^(lm&7))<<3);
    const int wrt = lm*128 + (((2*w + (lq>>1))^(lm&7))<<3) + ((lq&1)<<2);

    int nodeBase = blockIdx.x*64;
    const float* obp0 = &obs[(size_t)(nodeBase + lm)*256 + lq*8];

    for(int i=t;i<4096;i+=512) ((unsigned*)sH)[i] = 0u;   // zero sH buf 0 (16KB)
    float ho[4][4] = {{0.f,0.f,0.f,0.f},{0.f,0.f,0.f,0.f},
                      {0.f,0.f,0.f,0.f},{0.f,0.f,0.f,0.f}};

    float4 oA[4], oB[4];
    if(lq < 2){
        #pragma unroll
        for(int g=0; g<4; g++){
            const float* q = obp0 + (size_t)g*16*256;
            oA[g] = *(const float4*)(q);    oB[g] = *(const float4*)(q+4);
        }
    }
    #pragma unroll
    for(int g=0; g<4; g++){
        bf16x8 ob = (bf16x8){0,0,0,0,0,0,0,0};
        if(lq < 2){
            union { uint4 u; bf16x8 v; } cv;
            cv.u = make_uint4(cvtpk(oA[g].x,oA[g].y), cvtpk(oA[g].z,oA[g].w),
                              cvtpk(oB[g].x,oB[g].y), cvtpk(oB[g].z,oB[g].w));
            ob = cv.v;
        } else if(lq == 2){
            ob[0] = (short)0x3F80;          // k==16 -> bias row of WnT
        }
        f32x4 xa = (f32x4){0.f,0.f,0.f,0.f};
        xa = __builtin_amdgcn_mfma_f32_16x16x32_bf16(wfn, ob, xa, 0,0,0);
        unsigned u0 = cvtpk(fmaxf(xa[0],0.f), fmaxf(xa[1],0.f));
        unsigned u1 = cvtpk(fmaxf(xa[2],0.f), fmaxf(xa[3],0.f));
        *(uint2*)&sX[g*2048 + wrt] = make_uint2(u0,u1);
    }
    __syncthreads();

    int p = 0;
    #pragma unroll 1
    for(int s=0; s<T_; s++){
        if(s < T_-1 && lq < 2){
            #pragma unroll
            for(int g=0; g<4; g++){
                const float* q = obp0 + (size_t)g*16*256 + (s+1)*16;
                oA[g] = *(const float4*)(q);    oB[g] = *(const float4*)(q+4);
            }
        }
        #pragma unroll
        for(int g=0; g<4; g++){
            int base = p*8192 + g*2048;
            bf16x8 xb[4], hb[4];
            #pragma unroll
            for(int kt=0;kt<4;kt++){
                xb[kt] = *(const bf16x8*)&sX[base + rd[kt]];
                hb[kt] = *(const bf16x8*)&sH[base + rd[kt]];
            }
            f32x4 ar = b_r, az = b_z, axi = bxn, ahh = bhn;   // bias-in-C
            #pragma unroll
            for(int kt=0;kt<4;kt++){
                ar  = __builtin_amdgcn_mfma_f32_16x16x32_bf16(wfi[0][kt], xb[kt], ar, 0,0,0);
                az  = __builtin_amdgcn_mfma_f32_16x16x32_bf16(wfi[1][kt], xb[kt], az, 0,0,0);
                axi = __builtin_amdgcn_mfma_f32_16x16x32_bf16(wfi[2][kt], xb[kt], axi, 0,0,0);
                ar  = __builtin_amdgcn_mfma_f32_16x16x32_bf16(wfh[0][kt], hb[kt], ar, 0,0,0);
                az  = __builtin_amdgcn_mfma_f32_16x16x32_bf16(wfh[1][kt], hb[kt], az, 0,0,0);
                ahh = __builtin_amdgcn_mfma_f32_16x16x32_bf16(wfh[2][kt], hb[kt], ahh, 0,0,0);
            }
            #pragma unroll
            for(int v=0;v<4;v++){
                float r  = rcpf(1.f + exp2f(-ar[v]));
                float z  = rcpf(1.f + exp2f(-az[v]));
                float xn = fmaf(r, ahh[v], axi[v]);
                float nn = fmaf(2.f, rcpf(1.f + exp2f(-xn)), -1.f);
                ho[g][v] = nn + z*(ho[g][v] - nn);
            }
            unsigned u0 = cvtpk(ho[g][0], ho[g][1]);
            unsigned u1 = cvtpk(ho[g][2], ho[g][3]);
            *(uint2*)&sH[(p^1)*8192 + g*2048 + wrt] = make_uint2(u0,u1);
        }
        if(s < T_-1){
            #pragma unroll
            for(int g=0; g<4; g++){
                bf16x8 ob = (bf16x8){0,0,0,0,0,0,0,0};
                if(lq < 2){
                    union { uint4 u; bf16x8 v; } cv;
                    cv.u = make_uint4(cvtpk(oA[g].x,oA[g].y), cvtpk(oA[g].z,oA[g].w),
                                      cvtpk(oB[g].x,oB[g].y), cvtpk(oB[g].z,oB[g].w));
                    ob = cv.v;
                } else if(lq == 2){
                    ob[0] = (short)0x3F80;
                }
                f32x4 xa = (f32x4){0.f,0.f,0.f,0.f};
                xa = __builtin_amdgcn_mfma_f32_16x16x32_bf16(wfn, ob, xa, 0,0,0);
                unsigned u0 = cvtpk(fmaxf(xa[0],0.f), fmaxf(xa[1],0.f));
                unsigned u1 = cvtpk(fmaxf(xa[2],0.f), fmaxf(xa[3],0.f));
                *(uint2*)&sX[(p^1)*8192 + g*2048 + wrt] = make_uint2(u0,u1);
            }
        }
        __syncthreads();
        p ^= 1;
    }
    #pragma unroll
    for(int g=0; g<4; g++){
        unsigned u0 = cvtpk(ho[g][0], ho[g][1]);
        unsigned u1 = cvtpk(ho[g][2], ho[g][3]);
        *(uint2*)&hout[(size_t)(nodeBase + g*16 + lm)*H_ + cb] = make_uint2(u0,u1);
    }
}

// ---------- K3: xl|xr GEMM (blocks 0..624) | conv2 (blocks 625..880) ----------
__global__ __launch_bounds__(256) void k_xlxr_c2(const unsigned short* __restrict__ hb16,
        const unsigned short* __restrict__ WTb,
        unsigned short* __restrict__ xl, unsigned short* __restrict__ xr,
        const float* __restrict__ c1, const float* __restrict__ w2,
        const float* __restrict__ b2, float* __restrict__ c2out){
    int t = threadIdx.x;
    if(blockIdx.x < 625){
        int w = t>>6, lane = t&63, lq = lane>>4, lm = lane&15;
        int nb = blockIdx.x / 5, cgrp = blockIdx.x % 5;
        int nblk = nb*128;
        int ct0 = cgrp*16 + w*4;
        bf16x8 wf[4][4];
        #pragma unroll
        for(int i=0;i<4;i++){
            int row = (ct0+i)*16 + lm;
            #pragma unroll
            for(int kt=0;kt<4;kt++)
                wf[i][kt] = *(const bf16x8*)&WTb[(size_t)row*H_ + kt*32 + lq*8];
        }
        for(int g=0; g<8; g++){
            int node = nblk + g*16 + lm;
            bf16x8 hb[4];
            #pragma unroll
            for(int kt=0;kt<4;kt++)
                hb[kt] = *(const bf16x8*)&hb16[(size_t)node*H_ + kt*32 + lq*8];
            f32x4 acc[4];
            #pragma unroll
            for(int i=0;i<4;i++) acc[i] = (f32x4){0.f,0.f,0.f,0.f};
            #pragma unroll
            for(int kt=0;kt<4;kt++){
                #pragma unroll
                for(int i=0;i<4;i++)
                    acc[i] = __builtin_amdgcn_mfma_f32_16x16x32_bf16(wf[i][kt], hb[kt], acc[i], 0,0,0);
            }
            #pragma unroll
            for(int i=0;i<4;i++){
                int col = (ct0+i)*16 + lq*4;
                ushort4 o;
                o.x=f2bf(acc[i][0]); o.y=f2bf(acc[i][1]); o.z=f2bf(acc[i][2]); o.w=f2bf(acc[i][3]);
                if(col < HC) *(ushort4*)&xl[(size_t)node*HC + col] = o;
                else         *(ushort4*)&xr[(size_t)node*HC + (col-HC)] = o;
            }
        }
    } else {
        int idx = (blockIdx.x-625)*256 + t;
        int ox = idx & 7, oy = (idx>>3)&7, oc = (idx>>6)&63, b = idx>>12;
        float acc = b2[oc];
        for(int ic=0;ic<32;ic++){
            const float* ip = &c1[(size_t)((b*32+ic)*16)*16];
            const float* wp = &w2[(oc*32+ic)*9];
            #pragma unroll
            for(int ky=0;ky<3;ky++){
                int iy = oy*2+ky; if(iy>=16) continue;
                #pragma unroll
                for(int kx=0;kx<3;kx++){
                    int ix = ox*2+kx; if(ix>=16) continue;
                    acc = fmaf(ip[iy*16+ix], wp[ky*3+kx], acc);
                }
            }
        }
        c2out[idx] = fmaxf(acc, 0.f);
    }
}

// ---------------- edge src/dst helper ----------------
__device__ __forceinline__ void edge_sd(int e, const int* __restrict__ edges, int* src, int* dst){
    if(e < EG){
        int b = e / E_, j = e - b*E_;
        *src = edges[(b*2+0)*E_ + j] + b*N_;
        *dst = edges[(b*2+1)*E_ + j] + b*N_;
    } else { *src = *dst = e - EG; }
}

// ---------- K4: logits+exp+segsum, XCD-swizzled (blocks 0..4999) | temb (5000..5511) ----
__global__ __launch_bounds__(256) void k_logits_tb(const unsigned short* __restrict__ xl,
        const unsigned short* __restrict__ xr, const int* __restrict__ edges,
        const float* __restrict__ atta, float* __restrict__ pbuf,
        float* __restrict__ segsum,
        const float* __restrict__ c2, const float* __restrict__ Wc,
        float* __restrict__ tacc){
    __shared__ float sC[128];
    int t = threadIdx.x;
    if(blockIdx.x < 5000){
        int lb = (blockIdx.x & 7)*625 + (blockIdx.x >> 3);
        int lane = t & 63, w = t >> 6;
        float am[8], a4[8];
        #pragma unroll
        for(int j=0;j<8;j++) am[j] = atta[lane*8+j];
        #pragma unroll
        for(int j=0;j<8;j++) a4[j] = (lane<16) ? atta[512+lane*8+j] : 0.f;

        int e0 = lb*16 + w*4;
        int srcs[4], dsts[4];
        #pragma unroll
        for(int i=0;i<4;i++) edge_sd(e0+i, edges, &srcs[i], &dsts[i]);
        #pragma unroll
        for(int i=0;i<4;i++){
            const unsigned short* xls = &xl[(size_t)srcs[i]*HC];
            const unsigned short* xrd = &xr[(size_t)dsts[i]*HC];
            uint4 ul = *(const uint4*)&xls[lane*8];
            uint4 ur = *(const uint4*)&xrd[lane*8];
            uint4 tl = make_uint4(0,0,0,0), tr = make_uint4(0,0,0,0);
            if(lane < 16){
                tl = *(const uint4*)&xls[512+lane*8];
                tr = *(const uint4*)&xrd[512+lane*8];
            }
            float pm = 0.f, p4 = 0.f;
            {
                unsigned pl[4] = {ul.x,ul.y,ul.z,ul.w};
                unsigned pr[4] = {ur.x,ur.y,ur.z,ur.w};
                #pragma unroll
                for(int q=0;q<4;q++){
                    float s0 = bf2f((unsigned short)(pl[q]&0xFFFFu)) + bf2f((unsigned short)(pr[q]&0xFFFFu));
                    float s1 = bf2f((unsigned short)(pl[q]>>16))     + bf2f((unsigned short)(pr[q]>>16));
                    s0 = s0 > 0.f ? s0 : NEG_SLOPE*s0;
                    s1 = s1 > 0.f ? s1 : NEG_SLOPE*s1;
                    pm = fmaf(s0, am[2*q],   pm);
                    pm = fmaf(s1, am[2*q+1], pm);
                }
            }
            {
                unsigned ql[4] = {tl.x,tl.y,tl.z,tl.w};
                unsigned qr[4] = {tr.x,tr.y,tr.z,tr.w};
                #pragma unroll
                for(int q=0;q<4;q++){
                    float s0 = bf2f((unsigned short)(ql[q]&0xFFFFu)) + bf2f((unsigned short)(qr[q]&0xFFFFu));
                    float s1 = bf2f((unsigned short)(ql[q]>>16))     + bf2f((unsigned short)(qr[q]>>16));
                    s0 = s0 > 0.f ? s0 : NEG_SLOPE*s0;
                    s1 = s1 > 0.f ? s1 : NEG_SLOPE*s1;
                    p4 = fmaf(s0, a4[2*q],   p4);
                    p4 = fmaf(s1, a4[2*q+1], p4);
                }
            }
            #pragma unroll
            for(int off=1; off<16; off<<=1){
                pm += __shfl_xor(pm, off);
                p4 += __shfl_xor(p4, off);
            }
            if((lane & 15) == 0){
                int hh = lane >> 4;
                float p = __expf(pm);
                pbuf[(size_t)(e0+i)*HEADS + hh] = p;
                atomicAdd(&segsum[dsts[i]*HEADS + hh], p);
            }
            if(lane == 8){
                float p = __expf(p4);
                pbuf[(size_t)(e0+i)*HEADS + 4] = p;
                atomicAdd(&segsum[dsts[i]*HEADS + 4], p);
            }
        }
    } else {
        int bb = blockIdx.x - 5000;
        int b = bb >> 5, ks = bb & 31;
        int k0 = ks*128;
        if(t < 128) sC[t] = c2[(size_t)b*4096 + k0 + t];
        __syncthreads();
        int j = t & 127, sub = t >> 7;
        const float* wp = &Wc[(size_t)(k0 + sub*64)*H_ + j];
        const float* cp = &sC[sub*64];
        float a0=0.f, a1=0.f, a2=0.f, a3=0.f;
        #pragma unroll
        for(int kk=0; kk<64; kk+=4){
            a0 = fmaf(cp[kk+0], wp[(size_t)(kk+0)*H_], a0);
            a1 = fmaf(cp[kk+1], wp[(size_t)(kk+1)*H_], a1);
            a2 = fmaf(cp[kk+2], wp[(size_t)(kk+2)*H_], a2);
            a3 = fmaf(cp[kk+3], wp[(size_t)(kk+3)*H_], a3);
        }
        atomicAdd(&tacc[b*H_+j], (a0+a1)+(a2+a3));
    }
}

// ---------------- K5: alpha = p/segsum + wave-cooperative ego accumulation ----------
__global__ void k_alpha(const float* __restrict__ pbuf, const float* __restrict__ segsum,
                        const int* __restrict__ edges, const unsigned short* __restrict__ xl,
                        float* __restrict__ out_alpha, float* __restrict__ node_out){
    int idx = blockIdx.x*256 + threadIdx.x;
    int lane = threadIdx.x & 63;
    bool valid = idx < ETOT*HEADS;
    int e = 0, hh = 0, src = 0, dst = 0;
    float a = 0.f;
    bool ego = false;
    if(valid){
        e = idx / HEADS; hh = idx - e*HEADS;
        edge_sd(e, edges, &src, &dst);
        a = pbuf[idx] / segsum[dst*HEADS + hh];
        out_alpha[idx] = a;
        ego = (dst % N_) == 0;
    }
    unsigned long long m = __ballot(ego);
    while(m){
        int l = __ffsll((unsigned long long)m) - 1;
        m &= (m - 1);
        float aa = __shfl(a, l);
        int ss = __shfl(src, l), dd = __shfl(dst, l), hq = __shfl(hh, l);
        int b = dd / N_;
        unsigned u = *(const unsigned*)&xl[(size_t)ss*HC + hq*H_ + lane*2];
        float* no = &node_out[b*HC + hq*H_ + lane*2];
        atomicAdd(no,     aa * bf2f((unsigned short)(u & 0xFFFFu)));
        atomicAdd(no + 1, aa * bf2f((unsigned short)(u >> 16)));
    }
}

// ---------------- K6: head ----------------
__global__ __launch_bounds__(256) void k_head(const float* __restrict__ node_out,
        const float* __restrict__ gat_bias, const float* __restrict__ tacc,
        const float* __restrict__ bc, const float* __restrict__ phase,
        const float* __restrict__ Wp, const float* __restrict__ bp,
        const float* __restrict__ Wh, const float* __restrict__ bh,
        const float* __restrict__ Wo, const float* __restrict__ bo,
        const float* __restrict__ Wa, const float* __restrict__ ba,
        float* __restrict__ out){
    __shared__ float sF[16][268];
    __shared__ float sHid[16][132];
    int t = threadIdx.x;
    for(int i=t;i<B_*H_;i+=256){
        int b=i>>7, c=i&127;
        float s=0.f;
        #pragma unroll
        for(int hh=0;hh<HEADS;hh++) s += node_out[b*HC + hh*H_ + c];
        sF[b][c] = s*(1.0f/HEADS) + gat_bias[c];
    }
    for(int i=t;i<B_*H_;i+=256){
        int b=i>>7, c=i&127;
        sF[b][128+c] = fmaxf(tacc[i] + bc[c], 0.f);
    }
    if(t < B_*P_){
        int b=t>>3, p=t&7;
        float s=bp[p];
        #pragma unroll
        for(int q=0;q<P_;q++) s = fmaf(phase[b*P_+q], Wp[q*P_+p], s);
        sF[b][256+p] = fmaxf(s, 0.f);
    }
    __syncthreads();
    for(int i=t;i<B_*H_;i+=256){
        int b=i>>7, j=i&127;
        float s=bh[j];
        for(int k=0;k<2*H_+P_;k++) s = fmaf(sF[b][k], Wh[k*H_+j], s);
        sHid[b][j]=fmaxf(s,0.f);
    }
    __syncthreads();
    if(t < B_*A_){
        int b=t>>3, a=t&7;
        float v=bo[0], ad=ba[a];
        for(int k=0;k<H_;k++){ float hv=sHid[b][k]; v = fmaf(hv,Wo[k],v); ad = fmaf(hv,Wa[k*A_+a],ad); }
        float m = ad;
        m += __shfl_xor(m,1); m += __shfl_xor(m,2); m += __shfl_xor(m,4);
        m *= 0.125f;
        out[b*A_+a] = v + ad - m;
    }
}

extern "C" void kernel_launch(void* const* d_in, const int* in_sizes, int n_in,
                              void* d_out, int out_size, void* d_ws, size_t ws_size,
                              hipStream_t stream) {
    (void)in_sizes; (void)n_in; (void)out_size; (void)ws_size;
    const float* obs      = (const float*)d_in[0];
    const float* phase    = (const float*)d_in[1];
    const float* obs_map  = (const float*)d_in[2];
    const int*   edges    = (const int*)  d_in[3];
    const float* W_nbrs   = (const float*)d_in[5];
    const float* b_nbrs   = (const float*)d_in[6];
    const float* W_ih     = (const float*)d_in[7];
    const float* W_hh     = (const float*)d_in[8];
    const float* b_ih     = (const float*)d_in[9];
    const float* b_hh     = (const float*)d_in[10];
    const float* Wl       = (const float*)d_in[11];
    const float* Wr       = (const float*)d_in[12];
    const float* att_a    = (const float*)d_in[13];
    const float* gat_bias = (const float*)d_in[14];
    const float* conv1_w  = (const float*)d_in[15];
    const float* conv1_b  = (const float*)d_in[16];
    const float* conv2_w  = (const float*)d_in[17];
    const float* conv2_b  = (const float*)d_in[18];
    const float* Wc       = (const float*)d_in[19];
    const float* bc       = (const float*)d_in[20];
    const float* Wp       = (const float*)d_in[21];
    const float* bp       = (const float*)d_in[22];
    const float* Wh       = (const float*)d_in[23];
    const float* bh       = (const float*)d_in[24];
    const float* Wo       = (const float*)d_in[25];
    const float* bo       = (const float*)d_in[26];
    const float* Wa       = (const float*)d_in[27];
    const float* ba       = (const float*)d_in[28];

    float* out = (float*)d_out;                 // [0,128): out ; [128,400128): alpha
    float* w   = (float*)d_ws;

    size_t off = 0;
    unsigned short* hbuf = (unsigned short*)(w + off); off += (size_t)BN_*H_/2;
    unsigned short* xl   = (unsigned short*)(w + off); off += (size_t)BN_*HC/2;
    unsigned short* xr   = (unsigned short*)(w + off); off += (size_t)BN_*HC/2;
    float* pbuf   = w + off; off += (size_t)ETOT*HEADS;
    float* segsum = w + off; off += (size_t)BN_*HEADS;
    float* nodeo  = w + off; off += (size_t)B_*HC;
    float* c1     = w + off; off += (size_t)16*32*16*16;
    float* c2     = w + off; off += (size_t)16*64*8*8;
    float* tacc   = w + off; off += (size_t)B_*H_;
    unsigned short* Wihb = (unsigned short*)(w + off); off += (size_t)H_*G3/2;
    unsigned short* Whhb = (unsigned short*)(w + off); off += (size_t)H_*G3/2;
    unsigned short* WTb  = (unsigned short*)(w + off); off += (size_t)2*HC*H_/2;
    unsigned short* WnTb = (unsigned short*)(w + off); off += (size_t)H_*32/2;

    k_prep_c1<<<640 + 512, 256, 0, stream>>>(W_ih, W_hh, Wl, Wr, W_nbrs, b_nbrs,
                                             Wihb, Whhb, WTb, WnTb,
                                             segsum, nodeo, tacc,
                                             obs_map, conv1_w, conv1_b, c1);

    k_gruf<<<BN_/64, 512, 0, stream>>>(obs, WnTb, Wihb, b_ih, Whhb, b_hh, hbuf);

    k_xlxr_c2<<<625 + 256, 256, 0, stream>>>(hbuf, WTb, xl, xr,
                                             c1, conv2_w, conv2_b, c2);

    k_logits_tb<<<5000 + 512, 256, 0, stream>>>(xl, xr, edges, att_a, pbuf, segsum,
                                                c2, Wc, tacc);

    k_alpha<<<(ETOT*HEADS+255)/256, 256, 0, stream>>>(pbuf, segsum, edges, xl, out+128, nodeo);

    k_head<<<1, 256, 0, stream>>>(nodeo, gat_bias, tacc, bc, phase,
                                  Wp, bp, Wh, bh, Wo, bo, Wa, ba, out);
}

// Round 14
// 177.910 us; speedup vs baseline: 1.1412x; 1.1349x over previous
//
#include <hip/hip_runtime.h>
#include <hip/hip_bf16.h>
#include <math.h>

#define B_    16
#define N_    1000
#define BN_   16000
#define T_    16
#define FO    16
#define H_    128
#define G3    384       // 3*H
#define HEADS 5
#define HC    640       // heads*H
#define E_    4000
#define EG    64000     // B*E
#define ETOT  80000     // EG + BN self loops
#define P_    8
#define A_    8
#define NEG_SLOPE 0.2f

typedef __attribute__((ext_vector_type(8))) short bf16x8;
typedef __attribute__((ext_vector_type(4))) float f32x4;

__device__ __forceinline__ float bf2f(unsigned short u){ return __uint_as_float(((unsigned)u)<<16); }
__device__ __forceinline__ unsigned short f2bf(float x){
    unsigned u = __float_as_uint(x);
    unsigned r = (u + 0x7FFFu + ((u>>16)&1u)) >> 16;
    return (unsigned short)r;
}
__device__ __forceinline__ unsigned cvtpk(float lo, float hi){
    unsigned r;
    asm volatile("v_cvt_pk_bf16_f32 %0, %1, %2" : "=v"(r) : "v"(lo), "v"(hi));
    return r;
}
__device__ __forceinline__ float rcpf(float x){ return __builtin_amdgcn_rcpf(x); }

// ---------- K1: weight prep + init (blocks 0..639) | conv1 (blocks 640..1151) ----------
__global__ __launch_bounds__(256) void k_prep_c1(
        const float* __restrict__ Wih, const float* __restrict__ Whh,
        const float* __restrict__ Wl, const float* __restrict__ Wr,
        const float* __restrict__ Wn, const float* __restrict__ bn,
        unsigned short* __restrict__ Wihb, unsigned short* __restrict__ Whhb,
        unsigned short* __restrict__ WTb, unsigned short* __restrict__ WnTb,
        float* __restrict__ segsum, float* __restrict__ node_out,
        float* __restrict__ tacc,
        const float* __restrict__ im, const float* __restrict__ w1,
        const float* __restrict__ b1, float* __restrict__ c1out){
    __shared__ float sW[32*4*9];
    int t = threadIdx.x;
    if(blockIdx.x < 640){
        int i = blockIdx.x*256 + t;
        if(i < G3*H_){ Wihb[i] = f2bf(Wih[i]); Whhb[i] = f2bf(Whh[i]); }
        if(i < 2*HC*H_){
            int c = i >> 7, k = i & 127;
            float v = (c < HC) ? Wl[(size_t)k*HC + c] : Wr[(size_t)k*HC + (c-HC)];
            WTb[i] = f2bf(v);
        }
        if(i < H_*32){
            int c = i >> 5, k = i & 31;
            WnTb[i] = (k < FO) ? f2bf(Wn[k*H_ + c])
                     : (k == FO ? f2bf(bn[c]) : (unsigned short)0);
        }
        if(i < BN_*HEADS) segsum[i] = 0.0f;
        if(i < B_*HC) node_out[i] = 0.0f;
        if(i < B_*H_) tacc[i] = 0.0f;
    } else {
        for(int i=t;i<32*4*9;i+=256) sW[i]=w1[i];
        __syncthreads();
        int idx = (blockIdx.x-640)*256 + t;
        int ox = idx & 15, oy = (idx>>4)&15, oc = (idx>>8)&31, b = idx>>13;
        float acc = b1[oc];
        for(int ic=0;ic<4;ic++){
            const float* ip = &im[(size_t)((b*4+ic)*32)*32];
            const float* wp = &sW[(oc*4+ic)*9];
            #pragma unroll
            for(int ky=0;ky<3;ky++){
                int iy = oy*2+ky; if(iy>=32) continue;
                #pragma unroll
                for(int kx=0;kx<3;kx++){
                    int ix = ox*2+kx; if(ix>=32) continue;
                    acc = fmaf(ip[iy*32+ix], wp[ky*3+kx], acc);
                }
            }
        }
        c1out[idx] = fmaxf(acc, 0.f);
    }
}

// ============ K2: fused obs-MLP + gx + GRU (blocks 0..249, r11 structure) ============
//              | conv2 32->64, 16x16 -> 8x8 (blocks 250..377, 512 thr) ============
__global__ __launch_bounds__(512,2) void k_gruf(const float* __restrict__ obs,
        const unsigned short* __restrict__ WnTb,
        const unsigned short* __restrict__ Wihb, const float* __restrict__ bih,
        const unsigned short* __restrict__ Whhb, const float* __restrict__ bhh,
        unsigned short* __restrict__ hout,
        const float* __restrict__ c1, const float* __restrict__ w2,
        const float* __restrict__ b2, float* __restrict__ c2out){
    __shared__ unsigned short sX[2*8192];   // [buf][grp(4)][16 nodes][128], swizzled
    __shared__ unsigned short sH[2*8192];
    int t = threadIdx.x;

    if(blockIdx.x >= 250){   // ---- conv2 branch (fills idle CUs during GRU) ----
        int idx = (blockIdx.x-250)*512 + t;
        int ox = idx & 7, oy = (idx>>3)&7, oc = (idx>>6)&63, b = idx>>12;
        float acc = b2[oc];
        for(int ic=0;ic<32;ic++){
            const float* ip = &c1[(size_t)((b*32+ic)*16)*16];
            const float* wp = &w2[(oc*32+ic)*9];
            #pragma unroll
            for(int ky=0;ky<3;ky++){
                int iy = oy*2+ky; if(iy>=16) continue;
                #pragma unroll
                for(int kx=0;kx<3;kx++){
                    int ix = ox*2+kx; if(ix>=16) continue;
                    acc = fmaf(ip[iy*16+ix], wp[ky*3+kx], acc);
                }
            }
        }
        c2out[idx] = fmaxf(acc, 0.f);
        return;
    }

    int w = t>>6, lane = t&63, lq = lane>>4, lm = lane&15;

    bf16x8 wfi[3][4], wfh[3][4];
    #pragma unroll
    for(int i=0;i<3;i++){
        int row = (8*i + w)*16 + lm;
        #pragma unroll
        for(int kt=0;kt<4;kt++){
            wfi[i][kt] = *(const bf16x8*)&Wihb[row*H_ + kt*32 + lq*8];
            wfh[i][kt] = *(const bf16x8*)&Whhb[row*H_ + kt*32 + lq*8];
        }
    }
    bf16x8 wfn = *(const bf16x8*)&WnTb[(w*16+lm)*32 + lq*8];
    int cb = w*16 + lq*4;
    f32x4 b_r, b_z, bxn, bhn;
    { f32x4 t1=*(const f32x4*)&bih[cb],     t2=*(const f32x4*)&bhh[cb];     b_r=t1+t2; }
    { f32x4 t1=*(const f32x4*)&bih[128+cb], t2=*(const f32x4*)&bhh[128+cb]; b_z=t1+t2; }
    bxn = *(const f32x4*)&bih[256+cb];
    bhn = *(const f32x4*)&bhh[256+cb];

    int rd[4];
    #pragma unroll
    for(int kt=0;kt<4;kt++) rd[kt] = lm*128 + (((4*kt+lq)^(lm&7))<<3);
    const int wrt = lm*128 + (((2*w + (lq>>1))^(lm&7))<<3) + ((lq&1)<<2);

    int nodeBase = blockIdx.x*64;
    const float* obp0 = &obs[(size_t)(nodeBase + lm)*256 + lq*8];

    for(int i=t;i<4096;i+=512) ((unsigned*)sH)[i] = 0u;   // zero sH buf 0 (16KB)
    float ho[4][4] = {{0.f,0.f,0.f,0.f},{0.f,0.f,0.f,0.f},
                      {0.f,0.f,0.f,0.f},{0.f,0.f,0.f,0.f}};

    float4 oA[4], oB[4];
    if(lq < 2){
        #pragma unroll
        for(int g=0; g<4; g++){
            const float* q = obp0 + (size_t)g*16*256;
            oA[g] = *(const float4*)(q);    oB[g] = *(const float4*)(q+4);
        }
    }
    #pragma unroll
    for(int g=0; g<4; g++){
        bf16x8 ob = (bf16x8){0,0,0,0,0,0,0,0};
        if(lq < 2){
            union { uint4 u; bf16x8 v; } cv;
            cv.u = make_uint4(cvtpk(oA[g].x,oA[g].y), cvtpk(oA[g].z,oA[g].w),
                              cvtpk(oB[g].x,oB[g].y), cvtpk(oB[g].z,oB[g].w));
            ob = cv.v;
        } else if(lq == 2){
            ob[0] = (short)0x3F80;          // k==16 -> bias row of WnT
        }
        f32x4 xa = (f32x4){0.f,0.f,0.f,0.f};
        xa = __builtin_amdgcn_mfma_f32_16x16x32_bf16(wfn, ob, xa, 0,0,0);
        unsigned u0 = cvtpk(fmaxf(xa[0],0.f), fmaxf(xa[1],0.f));
        unsigned u1 = cvtpk(fmaxf(xa[2],0.f), fmaxf(xa[3],0.f));
        *(uint2*)&sX[g*2048 + wrt] = make_uint2(u0,u1);
    }
    __syncthreads();

    int p = 0;
    #pragma unroll 1
    for(int s=0; s<T_; s++){
        if(s < T_-1 && lq < 2){
            #pragma unroll
            for(int g=0; g<4; g++){
                const float* q = obp0 + (size_t)g*16*256 + (s+1)*16;
                oA[g] = *(const float4*)(q);    oB[g] = *(const float4*)(q+4);
            }
        }
        #pragma unroll
        for(int g=0; g<4; g++){
            int base = p*8192 + g*2048;
            bf16x8 xb[4], hb[4];
            #pragma unroll
            for(int kt=0;kt<4;kt++){
                xb[kt] = *(const bf16x8*)&sX[base + rd[kt]];
                hb[kt] = *(const bf16x8*)&sH[base + rd[kt]];
            }
            f32x4 ar = b_r, az = b_z, axi = bxn, ahh = bhn;   // bias-in-C
            #pragma unroll
            for(int kt=0;kt<4;kt++){
                ar  = __builtin_amdgcn_mfma_f32_16x16x32_bf16(wfi[0][kt], xb[kt], ar, 0,0,0);
                az  = __builtin_amdgcn_mfma_f32_16x16x32_bf16(wfi[1][kt], xb[kt], az, 0,0,0);
                axi = __builtin_amdgcn_mfma_f32_16x16x32_bf16(wfi[2][kt], xb[kt], axi, 0,0,0);
                ar  = __builtin_amdgcn_mfma_f32_16x16x32_bf16(wfh[0][kt], hb[kt], ar, 0,0,0);
                az  = __builtin_amdgcn_mfma_f32_16x16x32_bf16(wfh[1][kt], hb[kt], az, 0,0,0);
                ahh = __builtin_amdgcn_mfma_f32_16x16x32_bf16(wfh[2][kt], hb[kt], ahh, 0,0,0);
            }
            #pragma unroll
            for(int v=0;v<4;v++){
                float er = __expf(-ar[v]);
                float r  = rcpf(1.f + er);
                float ez = __expf(-az[v]);
                float z  = rcpf(1.f + ez);
                float xn = fmaf(r, ahh[v], axi[v]);
                float en = __expf(-2.f*xn);
                float nn = fmaf(2.f, rcpf(1.f + en), -1.f);
                ho[g][v] = nn + z*(ho[g][v] - nn);
            }
            unsigned u0 = cvtpk(ho[g][0], ho[g][1]);
            unsigned u1 = cvtpk(ho[g][2], ho[g][3]);
            *(uint2*)&sH[(p^1)*8192 + g*2048 + wrt] = make_uint2(u0,u1);
        }
        if(s < T_-1){
            #pragma unroll
            for(int g=0; g<4; g++){
                bf16x8 ob = (bf16x8){0,0,0,0,0,0,0,0};
                if(lq < 2){
                    union { uint4 u; bf16x8 v; } cv;
                    cv.u = make_uint4(cvtpk(oA[g].x,oA[g].y), cvtpk(oA[g].z,oA[g].w),
                                      cvtpk(oB[g].x,oB[g].y), cvtpk(oB[g].z,oB[g].w));
                    ob = cv.v;
                } else if(lq == 2){
                    ob[0] = (short)0x3F80;
                }
                f32x4 xa = (f32x4){0.f,0.f,0.f,0.f};
                xa = __builtin_amdgcn_mfma_f32_16x16x32_bf16(wfn, ob, xa, 0,0,0);
                unsigned u0 = cvtpk(fmaxf(xa[0],0.f), fmaxf(xa[1],0.f));
                unsigned u1 = cvtpk(fmaxf(xa[2],0.f), fmaxf(xa[3],0.f));
                *(uint2*)&sX[(p^1)*8192 + g*2048 + wrt] = make_uint2(u0,u1);
            }
        }
        __syncthreads();
        p ^= 1;
    }
    #pragma unroll
    for(int g=0; g<4; g++){
        unsigned u0 = cvtpk(ho[g][0], ho[g][1]);
        unsigned u1 = cvtpk(ho[g][2], ho[g][3]);
        *(uint2*)&hout[(size_t)(nodeBase + g*16 + lm)*H_ + cb] = make_uint2(u0,u1);
    }
}

// ---------- K3: xl|xr = h @ [Wl|Wr], MFMA bf16, 128 nodes/block (625 blocks) ----------
__global__ __launch_bounds__(256) void k_xlxr(const unsigned short* __restrict__ hb16,
        const unsigned short* __restrict__ WTb,
        unsigned short* __restrict__ xl, unsigned short* __restrict__ xr){
    int t = threadIdx.x;
    int w = t>>6, lane = t&63, lq = lane>>4, lm = lane&15;
    int nb = blockIdx.x / 5, cgrp = blockIdx.x % 5;
    int nblk = nb*128;
    int ct0 = cgrp*16 + w*4;
    bf16x8 wf[4][4];
    #pragma unroll
    for(int i=0;i<4;i++){
        int row = (ct0+i)*16 + lm;
        #pragma unroll
        for(int kt=0;kt<4;kt++)
            wf[i][kt] = *(const bf16x8*)&WTb[(size_t)row*H_ + kt*32 + lq*8];
    }
    for(int g=0; g<8; g++){
        int node = nblk + g*16 + lm;
        bf16x8 hb[4];
        #pragma unroll
        for(int kt=0;kt<4;kt++)
            hb[kt] = *(const bf16x8*)&hb16[(size_t)node*H_ + kt*32 + lq*8];
        f32x4 acc[4];
        #pragma unroll
        for(int i=0;i<4;i++) acc[i] = (f32x4){0.f,0.f,0.f,0.f};
        #pragma unroll
        for(int kt=0;kt<4;kt++){
            #pragma unroll
            for(int i=0;i<4;i++)
                acc[i] = __builtin_amdgcn_mfma_f32_16x16x32_bf16(wf[i][kt], hb[kt], acc[i], 0,0,0);
        }
        #pragma unroll
        for(int i=0;i<4;i++){
            int col = (ct0+i)*16 + lq*4;
            ushort4 o;
            o.x=f2bf(acc[i][0]); o.y=f2bf(acc[i][1]); o.z=f2bf(acc[i][2]); o.w=f2bf(acc[i][3]);
            if(col < HC) *(ushort4*)&xl[(size_t)node*HC + col] = o;
            else         *(ushort4*)&xr[(size_t)node*HC + (col-HC)] = o;
        }
    }
}

// ---------------- edge src/dst helper ----------------
__device__ __forceinline__ void edge_sd(int e, const int* __restrict__ edges, int* src, int* dst){
    if(e < EG){
        int b = e / E_, j = e - b*E_;
        *src = edges[(b*2+0)*E_ + j] + b*N_;
        *dst = edges[(b*2+1)*E_ + j] + b*N_;
    } else { *src = *dst = e - EG; }
}

// ---------- K4: logits+exp+segsum, XCD-swizzled (blocks 0..4999) | temb (5000..5511) ----
__global__ __launch_bounds__(256) void k_logits_tb(const unsigned short* __restrict__ xl,
        const unsigned short* __restrict__ xr, const int* __restrict__ edges,
        const float* __restrict__ atta, float* __restrict__ pbuf,
        float* __restrict__ segsum,
        const float* __restrict__ c2, const float* __restrict__ Wc,
        float* __restrict__ tacc){
    __shared__ float sC[128];
    int t = threadIdx.x;
    if(blockIdx.x < 5000){
        int lb = (blockIdx.x & 7)*625 + (blockIdx.x >> 3);
        int lane = t & 63, w = t >> 6;
        float am[8], a4[8];
        #pragma unroll
        for(int j=0;j<8;j++) am[j] = atta[lane*8+j];
        #pragma unroll
        for(int j=0;j<8;j++) a4[j] = (lane<16) ? atta[512+lane*8+j] : 0.f;

        int e0 = lb*16 + w*4;
        int srcs[4], dsts[4];
        #pragma unroll
        for(int i=0;i<4;i++) edge_sd(e0+i, edges, &srcs[i], &dsts[i]);
        #pragma unroll
        for(int i=0;i<4;i++){
            const unsigned short* xls = &xl[(size_t)srcs[i]*HC];
            const unsigned short* xrd = &xr[(size_t)dsts[i]*HC];
            uint4 ul = *(const uint4*)&xls[lane*8];
            uint4 ur = *(const uint4*)&xrd[lane*8];
            uint4 tl = make_uint4(0,0,0,0), tr = make_uint4(0,0,0,0);
            if(lane < 16){
                tl = *(const uint4*)&xls[512+lane*8];
                tr = *(const uint4*)&xrd[512+lane*8];
            }
            float pm = 0.f, p4 = 0.f;
            {
                unsigned pl[4] = {ul.x,ul.y,ul.z,ul.w};
                unsigned pr[4] = {ur.x,ur.y,ur.z,ur.w};
                #pragma unroll
                for(int q=0;q<4;q++){
                    float s0 = bf2f((unsigned short)(pl[q]&0xFFFFu)) + bf2f((unsigned short)(pr[q]&0xFFFFu));
                    float s1 = bf2f((unsigned short)(pl[q]>>16))     + bf2f((unsigned short)(pr[q]>>16));
                    s0 = s0 > 0.f ? s0 : NEG_SLOPE*s0;
                    s1 = s1 > 0.f ? s1 : NEG_SLOPE*s1;
                    pm = fmaf(s0, am[2*q],   pm);
                    pm = fmaf(s1, am[2*q+1], pm);
                }
            }
            {
                unsigned ql[4] = {tl.x,tl.y,tl.z,tl.w};
                unsigned qr[4] = {tr.x,tr.y,tr.z,tr.w};
                #pragma unroll
                for(int q=0;q<4;q++){
                    float s0 = bf2f((unsigned short)(ql[q]&0xFFFFu)) + bf2f((unsigned short)(qr[q]&0xFFFFu));
                    float s1 = bf2f((unsigned short)(ql[q]>>16))     + bf2f((unsigned short)(qr[q]>>16));
                    s0 = s0 > 0.f ? s0 : NEG_SLOPE*s0;
                    s1 = s1 > 0.f ? s1 : NEG_SLOPE*s1;
                    p4 = fmaf(s0, a4[2*q],   p4);
                    p4 = fmaf(s1, a4[2*q+1], p4);
                }
            }
            #pragma unroll
            for(int off=1; off<16; off<<=1){
                pm += __shfl_xor(pm, off);
                p4 += __shfl_xor(p4, off);
            }
            if((lane & 15) == 0){
                int hh = lane >> 4;
                float p = __expf(pm);
                pbuf[(size_t)(e0+i)*HEADS + hh] = p;
                atomicAdd(&segsum[dsts[i]*HEADS + hh], p);
            }
            if(lane == 8){
                float p = __expf(p4);
                pbuf[(size_t)(e0+i)*HEADS + 4] = p;
                atomicAdd(&segsum[dsts[i]*HEADS + 4], p);
            }
        }
    } else {
        int bb = blockIdx.x - 5000;
        int b = bb >> 5, ks = bb & 31;
        int k0 = ks*128;
        if(t < 128) sC[t] = c2[(size_t)b*4096 + k0 + t];
        __syncthreads();
        int j = t & 127, sub = t >> 7;
        const float* wp = &Wc[(size_t)(k0 + sub*64)*H_ + j];
        const float* cp = &sC[sub*64];
        float a0=0.f, a1=0.f, a2=0.f, a3=0.f;
        #pragma unroll
        for(int kk=0; kk<64; kk+=4){
            a0 = fmaf(cp[kk+0], wp[(size_t)(kk+0)*H_], a0);
            a1 = fmaf(cp[kk+1], wp[(size_t)(kk+1)*H_], a1);
            a2 = fmaf(cp[kk+2], wp[(size_t)(kk+2)*H_], a2);
            a3 = fmaf(cp[kk+3], wp[(size_t)(kk+3)*H_], a3);
        }
        atomicAdd(&tacc[b*H_+j], (a0+a1)+(a2+a3));
    }
}

// ---------------- K5: alpha = p/segsum + wave-cooperative ego accumulation ----------
__global__ void k_alpha(const float* __restrict__ pbuf, const float* __restrict__ segsum,
                        const int* __restrict__ edges, const unsigned short* __restrict__ xl,
                        float* __restrict__ out_alpha, float* __restrict__ node_out){
    int idx = blockIdx.x*256 + threadIdx.x;
    int lane = threadIdx.x & 63;
    bool valid = idx < ETOT*HEADS;
    int e = 0, hh = 0, src = 0, dst = 0;
    float a = 0.f;
    bool ego = false;
    if(valid){
        e = idx / HEADS; hh = idx - e*HEADS;
        edge_sd(e, edges, &src, &dst);
        a = pbuf[idx] / segsum[dst*HEADS + hh];
        out_alpha[idx] = a;
        ego = (dst % N_) == 0;
    }
    unsigned long long m = __ballot(ego);
    while(m){
        int l = __ffsll((unsigned long long)m) - 1;
        m &= (m - 1);
        float aa = __shfl(a, l);
        int ss = __shfl(src, l), dd = __shfl(dst, l), hq = __shfl(hh, l);
        int b = dd / N_;
        unsigned u = *(const unsigned*)&xl[(size_t)ss*HC + hq*H_ + lane*2];
        float* no = &node_out[b*HC + hq*H_ + lane*2];
        atomicAdd(no,     aa * bf2f((unsigned short)(u & 0xFFFFu)));
        atomicAdd(no + 1, aa * bf2f((unsigned short)(u >> 16)));
    }
}

// ---------------- K6: head, 16 blocks (one per sample) ----------------
__global__ __launch_bounds__(256) void k_head(const float* __restrict__ node_out,
        const float* __restrict__ gat_bias, const float* __restrict__ tacc,
        const float* __restrict__ bc, const float* __restrict__ phase,
        const float* __restrict__ Wp, const float* __restrict__ bp,
        const float* __restrict__ Wh, const float* __restrict__ bh,
        const float* __restrict__ Wo, const float* __restrict__ bo,
        const float* __restrict__ Wa, const float* __restrict__ ba,
        float* __restrict__ out){
    __shared__ float sF[268];
    __shared__ float sHid[128];
    int t = threadIdx.x;
    int b = blockIdx.x;
    if(t < 128){
        float s=0.f;
        #pragma unroll
        for(int hh=0;hh<HEADS;hh++) s += node_out[b*HC + hh*H_ + t];
        sF[t] = s*(1.0f/HEADS) + gat_bias[t];
    } else {
        int c = t - 128;
        sF[128+c] = fmaxf(tacc[b*H_ + c] + bc[c], 0.f);
    }
    if(t < P_){
        float s=bp[t];
        #pragma unroll
        for(int q=0;q<P_;q++) s = fmaf(phase[b*P_+q], Wp[q*P_+t], s);
        sF[256+t] = fmaxf(s, 0.f);
    }
    __syncthreads();
    if(t < 128){
        float s=bh[t];
        for(int k=0;k<2*H_+P_;k++) s = fmaf(sF[k], Wh[k*H_+t], s);
        sHid[t]=fmaxf(s,0.f);
    }
    __syncthreads();
    if(t < A_){
        float v=bo[0], ad=ba[t];
        for(int k=0;k<H_;k++){ float hv=sHid[k]; v = fmaf(hv,Wo[k],v); ad = fmaf(hv,Wa[k*A_+t],ad); }
        float m = ad;
        m += __shfl_xor(m,1); m += __shfl_xor(m,2); m += __shfl_xor(m,4);
        m *= 0.125f;
        out[b*A_+t] = v + ad - m;
    }
}

extern "C" void kernel_launch(void* const* d_in, const int* in_sizes, int n_in,
                              void* d_out, int out_size, void* d_ws, size_t ws_size,
                              hipStream_t stream) {
    (void)in_sizes; (void)n_in; (void)out_size; (void)ws_size;
    const float* obs      = (const float*)d_in[0];
    const float* phase    = (const float*)d_in[1];
    const float* obs_map  = (const float*)d_in[2];
    const int*   edges    = (const int*)  d_in[3];
    const float* W_nbrs   = (const float*)d_in[5];
    const float* b_nbrs   = (const float*)d_in[6];
    const float* W_ih     = (const float*)d_in[7];
    const float* W_hh     = (const float*)d_in[8];
    const float* b_ih     = (const float*)d_in[9];
    const float* b_hh     = (const float*)d_in[10];
    const float* Wl       = (const float*)d_in[11];
    const float* Wr       = (const float*)d_in[12];
    const float* att_a    = (const float*)d_in[13];
    const float* gat_bias = (const float*)d_in[14];
    const float* conv1_w  = (const float*)d_in[15];
    const float* conv1_b  = (const float*)d_in[16];
    const float* conv2_w  = (const float*)d_in[17];
    const float* conv2_b  = (const float*)d_in[18];
    const float* Wc       = (const float*)d_in[19];
    const float* bc       = (const float*)d_in[20];
    const float* Wp       = (const float*)d_in[21];
    const float* bp       = (const float*)d_in[22];
    const float* Wh       = (const float*)d_in[23];
    const float* bh       = (const float*)d_in[24];
    const float* Wo       = (const float*)d_in[25];
    const float* bo       = (const float*)d_in[26];
    const float* Wa       = (const float*)d_in[27];
    const float* ba       = (const float*)d_in[28];

    float* out = (float*)d_out;                 // [0,128): out ; [128,400128): alpha
    float* w   = (float*)d_ws;

    size_t off = 0;
    unsigned short* hbuf = (unsigned short*)(w + off); off += (size_t)BN_*H_/2;
    unsigned short* xl   = (unsigned short*)(w + off); off += (size_t)BN_*HC/2;
    unsigned short* xr   = (unsigned short*)(w + off); off += (size_t)BN_*HC/2;
    float* pbuf   = w + off; off += (size_t)ETOT*HEADS;
    float* segsum = w + off; off += (size_t)BN_*HEADS;
    float* nodeo  = w + off; off += (size_t)B_*HC;
    float* c1     = w + off; off += (size_t)16*32*16*16;
    float* c2     = w + off; off += (size_t)16*64*8*8;
    float* tacc   = w + off; off += (size_t)B_*H_;
    unsigned short* Wihb = (unsigned short*)(w + off); off += (size_t)H_*G3/2;
    unsigned short* Whhb = (unsigned short*)(w + off); off += (size_t)H_*G3/2;
    unsigned short* WTb  = (unsigned short*)(w + off); off += (size_t)2*HC*H_/2;
    unsigned short* WnTb = (unsigned short*)(w + off); off += (size_t)H_*32/2;

    k_prep_c1<<<640 + 512, 256, 0, stream>>>(W_ih, W_hh, Wl, Wr, W_nbrs, b_nbrs,
                                             Wihb, Whhb, WTb, WnTb,
                                             segsum, nodeo, tacc,
                                             obs_map, conv1_w, conv1_b, c1);

    k_gruf<<<250 + 128, 512, 0, stream>>>(obs, WnTb, Wihb, b_ih, Whhb, b_hh, hbuf,
                                          c1, conv2_w, conv2_b, c2);

    k_xlxr<<<625, 256, 0, stream>>>(hbuf, WTb, xl, xr);

    k_logits_tb<<<5000 + 512, 256, 0, stream>>>(xl, xr, edges, att_a, pbuf, segsum,
                                                c2, Wc, tacc);

    k_alpha<<<(ETOT*HEADS+255)/256, 256, 0, stream>>>(pbuf, segsum, edges, xl, out+128, nodeo);

    k_head<<<B_, 256, 0, stream>>>(nodeo, gat_bias, tacc, bc, phase,
                                   Wp, bp, Wh, bh, Wo, bo, Wa, ba, out);
}

// Round 15
// 169.211 us; speedup vs baseline: 1.1998x; 1.0514x over previous
//
#include <hip/hip_runtime.h>
#include <hip/hip_bf16.h>
#include <math.h>

#define B_    16
#define N_    1000
#define BN_   16000
#define T_    16
#define FO    16
#define H_    128
#define G3    384       // 3*H
#define HEADS 5
#define HC    640       // heads*H
#define E_    4000
#define EG    64000     // B*E
#define ETOT  80000     // EG + BN self loops
#define P_    8
#define A_    8
#define NEG_SLOPE 0.2f

typedef __attribute__((ext_vector_type(8))) short bf16x8;
typedef __attribute__((ext_vector_type(4))) float f32x4;

__device__ __forceinline__ float bf2f(unsigned short u){ return __uint_as_float(((unsigned)u)<<16); }
__device__ __forceinline__ unsigned short f2bf(float x){
    unsigned u = __float_as_uint(x);
    unsigned r = (u + 0x7FFFu + ((u>>16)&1u)) >> 16;
    return (unsigned short)r;
}
__device__ __forceinline__ unsigned cvtpk(float lo, float hi){
    unsigned r;
    asm volatile("v_cvt_pk_bf16_f32 %0, %1, %2" : "=v"(r) : "v"(lo), "v"(hi));
    return r;
}
__device__ __forceinline__ float rcpf(float x){ return __builtin_amdgcn_rcpf(x); }

// ---------- K1: weight prep + init (blocks 0..639) | conv1 (blocks 640..1151) ----------
__global__ __launch_bounds__(256) void k_prep_c1(
        const float* __restrict__ Wih, const float* __restrict__ Whh,
        const float* __restrict__ Wl, const float* __restrict__ Wr,
        const float* __restrict__ Wn, const float* __restrict__ bn,
        unsigned short* __restrict__ Wihb, unsigned short* __restrict__ Whhb,
        unsigned short* __restrict__ WTb, unsigned short* __restrict__ WnTb,
        float* __restrict__ segsum, float* __restrict__ node_out,
        float* __restrict__ tacc,
        const float* __restrict__ im, const float* __restrict__ w1,
        const float* __restrict__ b1, float* __restrict__ c1out){
    __shared__ float sW[32*4*9];
    int t = threadIdx.x;
    if(blockIdx.x < 640){
        int i = blockIdx.x*256 + t;
        if(i < G3*H_){ Wihb[i] = f2bf(Wih[i]); Whhb[i] = f2bf(Whh[i]); }
        if(i < 2*HC*H_){
            int c = i >> 7, k = i & 127;
            float v = (c < HC) ? Wl[(size_t)k*HC + c] : Wr[(size_t)k*HC + (c-HC)];
            WTb[i] = f2bf(v);
        }
        if(i < H_*32){
            int c = i >> 5, k = i & 31;
            WnTb[i] = (k < FO) ? f2bf(Wn[k*H_ + c])
                     : (k == FO ? f2bf(bn[c]) : (unsigned short)0);
        }
        if(i < BN_*HEADS) segsum[i] = 0.0f;
        if(i < B_*HC) node_out[i] = 0.0f;
        if(i < B_*H_) tacc[i] = 0.0f;
    } else {
        for(int i=t;i<32*4*9;i+=256) sW[i]=w1[i];
        __syncthreads();
        int idx = (blockIdx.x-640)*256 + t;
        int ox = idx & 15, oy = (idx>>4)&15, oc = (idx>>8)&31, b = idx>>13;
        float acc = b1[oc];
        for(int ic=0;ic<4;ic++){
            const float* ip = &im[(size_t)((b*4+ic)*32)*32];
            const float* wp = &sW[(oc*4+ic)*9];
            #pragma unroll
            for(int ky=0;ky<3;ky++){
                int iy = oy*2+ky; if(iy>=32) continue;
                #pragma unroll
                for(int kx=0;kx<3;kx++){
                    int ix = ox*2+kx; if(ix>=32) continue;
                    acc = fmaf(ip[iy*32+ix], wp[ky*3+kx], acc);
                }
            }
        }
        c1out[idx] = fmaxf(acc, 0.f);
    }
}

// ============ K2: fused obs-MLP + gx + GRU, 64 nodes/block, 250 blocks (pure) ============
__global__ __launch_bounds__(512,2) void k_gruf(const float* __restrict__ obs,
        const unsigned short* __restrict__ WnTb,
        const unsigned short* __restrict__ Wihb, const float* __restrict__ bih,
        const unsigned short* __restrict__ Whhb, const float* __restrict__ bhh,
        unsigned short* __restrict__ hout){
    __shared__ unsigned short sX[2*8192];   // [buf][grp(4)][16 nodes][128], swizzled
    __shared__ unsigned short sH[2*8192];
    int t = threadIdx.x;
    int w = t>>6, lane = t&63, lq = lane>>4, lm = lane&15;

    bf16x8 wfi[3][4], wfh[3][4];
    #pragma unroll
    for(int i=0;i<3;i++){
        int row = (8*i + w)*16 + lm;
        #pragma unroll
        for(int kt=0;kt<4;kt++){
            wfi[i][kt] = *(const bf16x8*)&Wihb[row*H_ + kt*32 + lq*8];
            wfh[i][kt] = *(const bf16x8*)&Whhb[row*H_ + kt*32 + lq*8];
        }
    }
    bf16x8 wfn = *(const bf16x8*)&WnTb[(w*16+lm)*32 + lq*8];
    int cb = w*16 + lq*4;
    f32x4 b_r, b_z, bxn, bhn;
    { f32x4 t1=*(const f32x4*)&bih[cb],     t2=*(const f32x4*)&bhh[cb];     b_r=t1+t2; }
    { f32x4 t1=*(const f32x4*)&bih[128+cb], t2=*(const f32x4*)&bhh[128+cb]; b_z=t1+t2; }
    bxn = *(const f32x4*)&bih[256+cb];
    bhn = *(const f32x4*)&bhh[256+cb];

    int rd[4];
    #pragma unroll
    for(int kt=0;kt<4;kt++) rd[kt] = lm*128 + (((4*kt+lq)^(lm&7))<<3);
    const int wrt = lm*128 + (((2*w + (lq>>1))^(lm&7))<<3) + ((lq&1)<<2);

    int nodeBase = blockIdx.x*64;
    const float* obp0 = &obs[(size_t)(nodeBase + lm)*256 + lq*8];

    for(int i=t;i<4096;i+=512) ((unsigned*)sH)[i] = 0u;   // zero sH buf 0 (16KB)
    float ho[4][4] = {{0.f,0.f,0.f,0.f},{0.f,0.f,0.f,0.f},
                      {0.f,0.f,0.f,0.f},{0.f,0.f,0.f,0.f}};

    float4 oA[4], oB[4];
    if(lq < 2){
        #pragma unroll
        for(int g=0; g<4; g++){
            const float* q = obp0 + (size_t)g*16*256;
            oA[g] = *(const float4*)(q);    oB[g] = *(const float4*)(q+4);
        }
    }
    #pragma unroll
    for(int g=0; g<4; g++){
        bf16x8 ob = (bf16x8){0,0,0,0,0,0,0,0};
        if(lq < 2){
            union { uint4 u; bf16x8 v; } cv;
            cv.u = make_uint4(cvtpk(oA[g].x,oA[g].y), cvtpk(oA[g].z,oA[g].w),
                              cvtpk(oB[g].x,oB[g].y), cvtpk(oB[g].z,oB[g].w));
            ob = cv.v;
        } else if(lq == 2){
            ob[0] = (short)0x3F80;          // k==16 -> bias row of WnT
        }
        f32x4 xa = (f32x4){0.f,0.f,0.f,0.f};
        xa = __builtin_amdgcn_mfma_f32_16x16x32_bf16(wfn, ob, xa, 0,0,0);
        unsigned u0 = cvtpk(fmaxf(xa[0],0.f), fmaxf(xa[1],0.f));
        unsigned u1 = cvtpk(fmaxf(xa[2],0.f), fmaxf(xa[3],0.f));
        *(uint2*)&sX[g*2048 + wrt] = make_uint2(u0,u1);
    }
    __syncthreads();

    int p = 0;
    #pragma unroll 1
    for(int s=0; s<T_; s++){
        if(s < T_-1 && lq < 2){
            #pragma unroll
            for(int g=0; g<4; g++){
                const float* q = obp0 + (size_t)g*16*256 + (s+1)*16;
                oA[g] = *(const float4*)(q);    oB[g] = *(const float4*)(q+4);
            }
        }
        #pragma unroll
        for(int g=0; g<4; g++){
            int base = p*8192 + g*2048;
            bf16x8 xb[4], hb[4];
            #pragma unroll
            for(int kt=0;kt<4;kt++){
                xb[kt] = *(const bf16x8*)&sX[base + rd[kt]];
                hb[kt] = *(const bf16x8*)&sH[base + rd[kt]];
            }
            f32x4 ar = b_r, az = b_z, axi = bxn, ahh = bhn;   // bias-in-C
            #pragma unroll
            for(int kt=0;kt<4;kt++){
                ar  = __builtin_amdgcn_mfma_f32_16x16x32_bf16(wfi[0][kt], xb[kt], ar, 0,0,0);
                az  = __builtin_amdgcn_mfma_f32_16x16x32_bf16(wfi[1][kt], xb[kt], az, 0,0,0);
                axi = __builtin_amdgcn_mfma_f32_16x16x32_bf16(wfi[2][kt], xb[kt], axi, 0,0,0);
                ar  = __builtin_amdgcn_mfma_f32_16x16x32_bf16(wfh[0][kt], hb[kt], ar, 0,0,0);
                az  = __builtin_amdgcn_mfma_f32_16x16x32_bf16(wfh[1][kt], hb[kt], az, 0,0,0);
                ahh = __builtin_amdgcn_mfma_f32_16x16x32_bf16(wfh[2][kt], hb[kt], ahh, 0,0,0);
            }
            #pragma unroll
            for(int v=0;v<4;v++){
                float er = __expf(-ar[v]);
                float r  = rcpf(1.f + er);
                float ez = __expf(-az[v]);
                float z  = rcpf(1.f + ez);
                float xn = fmaf(r, ahh[v], axi[v]);
                float en = __expf(-2.f*xn);
                float nn = fmaf(2.f, rcpf(1.f + en), -1.f);
                ho[g][v] = nn + z*(ho[g][v] - nn);
            }
            unsigned u0 = cvtpk(ho[g][0], ho[g][1]);
            unsigned u1 = cvtpk(ho[g][2], ho[g][3]);
            *(uint2*)&sH[(p^1)*8192 + g*2048 + wrt] = make_uint2(u0,u1);
        }
        if(s < T_-1){
            #pragma unroll
            for(int g=0; g<4; g++){
                bf16x8 ob = (bf16x8){0,0,0,0,0,0,0,0};
                if(lq < 2){
                    union { uint4 u; bf16x8 v; } cv;
                    cv.u = make_uint4(cvtpk(oA[g].x,oA[g].y), cvtpk(oA[g].z,oA[g].w),
                                      cvtpk(oB[g].x,oB[g].y), cvtpk(oB[g].z,oB[g].w));
                    ob = cv.v;
                } else if(lq == 2){
                    ob[0] = (short)0x3F80;
                }
                f32x4 xa = (f32x4){0.f,0.f,0.f,0.f};
                xa = __builtin_amdgcn_mfma_f32_16x16x32_bf16(wfn, ob, xa, 0,0,0);
                unsigned u0 = cvtpk(fmaxf(xa[0],0.f), fmaxf(xa[1],0.f));
                unsigned u1 = cvtpk(fmaxf(xa[2],0.f), fmaxf(xa[3],0.f));
                *(uint2*)&sX[(p^1)*8192 + g*2048 + wrt] = make_uint2(u0,u1);
            }
        }
        __syncthreads();
        p ^= 1;
    }
    #pragma unroll
    for(int g=0; g<4; g++){
        unsigned u0 = cvtpk(ho[g][0], ho[g][1]);
        unsigned u1 = cvtpk(ho[g][2], ho[g][3]);
        *(uint2*)&hout[(size_t)(nodeBase + g*16 + lm)*H_ + cb] = make_uint2(u0,u1);
    }
}

// ---------- K3: xl|xr GEMM (blocks 0..624) | conv2 (blocks 625..880) ----------
__global__ __launch_bounds__(256) void k_xlxr_c2(const unsigned short* __restrict__ hb16,
        const unsigned short* __restrict__ WTb,
        unsigned short* __restrict__ xl, unsigned short* __restrict__ xr,
        const float* __restrict__ c1, const float* __restrict__ w2,
        const float* __restrict__ b2, float* __restrict__ c2out){
    int t = threadIdx.x;
    if(blockIdx.x < 625){
        int w = t>>6, lane = t&63, lq = lane>>4, lm = lane&15;
        int nb = blockIdx.x / 5, cgrp = blockIdx.x % 5;
        int nblk = nb*128;
        int ct0 = cgrp*16 + w*4;
        bf16x8 wf[4][4];
        #pragma unroll
        for(int i=0;i<4;i++){
            int row = (ct0+i)*16 + lm;
            #pragma unroll
            for(int kt=0;kt<4;kt++)
                wf[i][kt] = *(const bf16x8*)&WTb[(size_t)row*H_ + kt*32 + lq*8];
        }
        for(int g=0; g<8; g++){
            int node = nblk + g*16 + lm;
            bf16x8 hb[4];
            #pragma unroll
            for(int kt=0;kt<4;kt++)
                hb[kt] = *(const bf16x8*)&hb16[(size_t)node*H_ + kt*32 + lq*8];
            f32x4 acc[4];
            #pragma unroll
            for(int i=0;i<4;i++) acc[i] = (f32x4){0.f,0.f,0.f,0.f};
            #pragma unroll
            for(int kt=0;kt<4;kt++){
                #pragma unroll
                for(int i=0;i<4;i++)
                    acc[i] = __builtin_amdgcn_mfma_f32_16x16x32_bf16(wf[i][kt], hb[kt], acc[i], 0,0,0);
            }
            #pragma unroll
            for(int i=0;i<4;i++){
                int col = (ct0+i)*16 + lq*4;
                ushort4 o;
                o.x=f2bf(acc[i][0]); o.y=f2bf(acc[i][1]); o.z=f2bf(acc[i][2]); o.w=f2bf(acc[i][3]);
                if(col < HC) *(ushort4*)&xl[(size_t)node*HC + col] = o;
                else         *(ushort4*)&xr[(size_t)node*HC + (col-HC)] = o;
            }
        }
    } else {
        int idx = (blockIdx.x-625)*256 + t;
        int ox = idx & 7, oy = (idx>>3)&7, oc = (idx>>6)&63, b = idx>>12;
        float acc = b2[oc];
        for(int ic=0;ic<32;ic++){
            const float* ip = &c1[(size_t)((b*32+ic)*16)*16];
            const float* wp = &w2[(oc*32+ic)*9];
            #pragma unroll
            for(int ky=0;ky<3;ky++){
                int iy = oy*2+ky; if(iy>=16) continue;
                #pragma unroll
                for(int kx=0;kx<3;kx++){
                    int ix = ox*2+kx; if(ix>=16) continue;
                    acc = fmaf(ip[iy*16+ix], wp[ky*3+kx], acc);
                }
            }
        }
        c2out[idx] = fmaxf(acc, 0.f);
    }
}

// ---------------- edge src/dst helper ----------------
__device__ __forceinline__ void edge_sd(int e, const int* __restrict__ edges, int* src, int* dst){
    if(e < EG){
        int b = e / E_, j = e - b*E_;
        *src = edges[(b*2+0)*E_ + j] + b*N_;
        *dst = edges[(b*2+1)*E_ + j] + b*N_;
    } else { *src = *dst = e - EG; }
}

// ---------- K4: logits+exp+segsum, XCD-swizzled (blocks 0..4999) | temb (5000..5511) ----
__global__ __launch_bounds__(256) void k_logits_tb(const unsigned short* __restrict__ xl,
        const unsigned short* __restrict__ xr, const int* __restrict__ edges,
        const float* __restrict__ atta, float* __restrict__ pbuf,
        float* __restrict__ segsum,
        const float* __restrict__ c2, const float* __restrict__ Wc,
        float* __restrict__ tacc){
    __shared__ float sC[128];
    int t = threadIdx.x;
    if(blockIdx.x < 5000){
        int lb = (blockIdx.x & 7)*625 + (blockIdx.x >> 3);
        int lane = t & 63, w = t >> 6;
        float am[8], a4[8];
        #pragma unroll
        for(int j=0;j<8;j++) am[j] = atta[lane*8+j];
        #pragma unroll
        for(int j=0;j<8;j++) a4[j] = (lane<16) ? atta[512+lane*8+j] : 0.f;

        int e0 = lb*16 + w*4;
        int srcs[4], dsts[4];
        #pragma unroll
        for(int i=0;i<4;i++) edge_sd(e0+i, edges, &srcs[i], &dsts[i]);
        #pragma unroll
        for(int i=0;i<4;i++){
            const unsigned short* xls = &xl[(size_t)srcs[i]*HC];
            const unsigned short* xrd = &xr[(size_t)dsts[i]*HC];
            uint4 ul = *(const uint4*)&xls[lane*8];
            uint4 ur = *(const uint4*)&xrd[lane*8];
            uint4 tl = make_uint4(0,0,0,0), tr = make_uint4(0,0,0,0);
            if(lane < 16){
                tl = *(const uint4*)&xls[512+lane*8];
                tr = *(const uint4*)&xrd[512+lane*8];
            }
            float pm = 0.f, p4 = 0.f;
            {
                unsigned pl[4] = {ul.x,ul.y,ul.z,ul.w};
                unsigned pr[4] = {ur.x,ur.y,ur.z,ur.w};
                #pragma unroll
                for(int q=0;q<4;q++){
                    float s0 = bf2f((unsigned short)(pl[q]&0xFFFFu)) + bf2f((unsigned short)(pr[q]&0xFFFFu));
                    float s1 = bf2f((unsigned short)(pl[q]>>16))     + bf2f((unsigned short)(pr[q]>>16));
                    s0 = s0 > 0.f ? s0 : NEG_SLOPE*s0;
                    s1 = s1 > 0.f ? s1 : NEG_SLOPE*s1;
                    pm = fmaf(s0, am[2*q],   pm);
                    pm = fmaf(s1, am[2*q+1], pm);
                }
            }
            {
                unsigned ql[4] = {tl.x,tl.y,tl.z,tl.w};
                unsigned qr[4] = {tr.x,tr.y,tr.z,tr.w};
                #pragma unroll
                for(int q=0;q<4;q++){
                    float s0 = bf2f((unsigned short)(ql[q]&0xFFFFu)) + bf2f((unsigned short)(qr[q]&0xFFFFu));
                    float s1 = bf2f((unsigned short)(ql[q]>>16))     + bf2f((unsigned short)(qr[q]>>16));
                    s0 = s0 > 0.f ? s0 : NEG_SLOPE*s0;
                    s1 = s1 > 0.f ? s1 : NEG_SLOPE*s1;
                    p4 = fmaf(s0, a4[2*q],   p4);
                    p4 = fmaf(s1, a4[2*q+1], p4);
                }
            }
            #pragma unroll
            for(int off=1; off<16; off<<=1){
                pm += __shfl_xor(pm, off);
                p4 += __shfl_xor(p4, off);
            }
            if((lane & 15) == 0){
                int hh = lane >> 4;
                float p = __expf(pm);
                pbuf[(size_t)(e0+i)*HEADS + hh] = p;
                atomicAdd(&segsum[dsts[i]*HEADS + hh], p);
            }
            if(lane == 8){
                float p = __expf(p4);
                pbuf[(size_t)(e0+i)*HEADS + 4] = p;
                atomicAdd(&segsum[dsts[i]*HEADS + 4], p);
            }
        }
    } else {
        int bb = blockIdx.x - 5000;
        int b = bb >> 5, ks = bb & 31;
        int k0 = ks*128;
        if(t < 128) sC[t] = c2[(size_t)b*4096 + k0 + t];
        __syncthreads();
        int j = t & 127, sub = t >> 7;
        const float* wp = &Wc[(size_t)(k0 + sub*64)*H_ + j];
        const float* cp = &sC[sub*64];
        float a0=0.f, a1=0.f, a2=0.f, a3=0.f;
        #pragma unroll
        for(int kk=0; kk<64; kk+=4){
            a0 = fmaf(cp[kk+0], wp[(size_t)(kk+0)*H_], a0);
            a1 = fmaf(cp[kk+1], wp[(size_t)(kk+1)*H_], a1);
            a2 = fmaf(cp[kk+2], wp[(size_t)(kk+2)*H_], a2);
            a3 = fmaf(cp[kk+3], wp[(size_t)(kk+3)*H_], a3);
        }
        atomicAdd(&tacc[b*H_+j], (a0+a1)+(a2+a3));
    }
}

// ---------------- K5: alpha = p/segsum + wave-cooperative ego accumulation ----------
__global__ void k_alpha(const float* __restrict__ pbuf, const float* __restrict__ segsum,
                        const int* __restrict__ edges, const unsigned short* __restrict__ xl,
                        float* __restrict__ out_alpha, float* __restrict__ node_out){
    int idx = blockIdx.x*256 + threadIdx.x;
    int lane = threadIdx.x & 63;
    bool valid = idx < ETOT*HEADS;
    int e = 0, hh = 0, src = 0, dst = 0;
    float a = 0.f;
    bool ego = false;
    if(valid){
        e = idx / HEADS; hh = idx - e*HEADS;
        edge_sd(e, edges, &src, &dst);
        a = pbuf[idx] / segsum[dst*HEADS + hh];
        out_alpha[idx] = a;
        ego = (dst % N_) == 0;
    }
    unsigned long long m = __ballot(ego);
    while(m){
        int l = __ffsll((unsigned long long)m) - 1;
        m &= (m - 1);
        float aa = __shfl(a, l);
        int ss = __shfl(src, l), dd = __shfl(dst, l), hq = __shfl(hh, l);
        int b = dd / N_;
        unsigned u = *(const unsigned*)&xl[(size_t)ss*HC + hq*H_ + lane*2];
        float* no = &node_out[b*HC + hq*H_ + lane*2];
        atomicAdd(no,     aa * bf2f((unsigned short)(u & 0xFFFFu)));
        atomicAdd(no + 1, aa * bf2f((unsigned short)(u >> 16)));
    }
}

// ---------------- K6: head, 16 blocks (one per sample) ----------------
__global__ __launch_bounds__(256) void k_head(const float* __restrict__ node_out,
        const float* __restrict__ gat_bias, const float* __restrict__ tacc,
        const float* __restrict__ bc, const float* __restrict__ phase,
        const float* __restrict__ Wp, const float* __restrict__ bp,
        const float* __restrict__ Wh, const float* __restrict__ bh,
        const float* __restrict__ Wo, const float* __restrict__ bo,
        const float* __restrict__ Wa, const float* __restrict__ ba,
        float* __restrict__ out){
    __shared__ float sF[268];
    __shared__ float sHid[128];
    int t = threadIdx.x;
    int b = blockIdx.x;
    if(t < 128){
        float s=0.f;
        #pragma unroll
        for(int hh=0;hh<HEADS;hh++) s += node_out[b*HC + hh*H_ + t];
        sF[t] = s*(1.0f/HEADS) + gat_bias[t];
    } else {
        int c = t - 128;
        sF[128+c] = fmaxf(tacc[b*H_ + c] + bc[c], 0.f);
    }
    if(t < P_){
        float s=bp[t];
        #pragma unroll
        for(int q=0;q<P_;q++) s = fmaf(phase[b*P_+q], Wp[q*P_+t], s);
        sF[256+t] = fmaxf(s, 0.f);
    }
    __syncthreads();
    if(t < 128){
        float s=bh[t];
        for(int k=0;k<2*H_+P_;k++) s = fmaf(sF[k], Wh[k*H_+t], s);
        sHid[t]=fmaxf(s,0.f);
    }
    __syncthreads();
    if(t < A_){
        float v=bo[0], ad=ba[t];
        for(int k=0;k<H_;k++){ float hv=sHid[k]; v = fmaf(hv,Wo[k],v); ad = fmaf(hv,Wa[k*A_+t],ad); }
        float m = ad;
        m += __shfl_xor(m,1); m += __shfl_xor(m,2); m += __shfl_xor(m,4);
        m *= 0.125f;
        out[b*A_+t] = v + ad - m;
    }
}

extern "C" void kernel_launch(void* const* d_in, const int* in_sizes, int n_in,
                              void* d_out, int out_size, void* d_ws, size_t ws_size,
                              hipStream_t stream) {
    (void)in_sizes; (void)n_in; (void)out_size; (void)ws_size;
    const float* obs      = (const float*)d_in[0];
    const float* phase    = (const float*)d_in[1];
    const float* obs_map  = (const float*)d_in[2];
    const int*   edges    = (const int*)  d_in[3];
    const float* W_nbrs   = (const float*)d_in[5];
    const float* b_nbrs   = (const float*)d_in[6];
    const float* W_ih     = (const float*)d_in[7];
    const float* W_hh     = (const float*)d_in[8];
    const float* b_ih     = (const float*)d_in[9];
    const float* b_hh     = (const float*)d_in[10];
    const float* Wl       = (const float*)d_in[11];
    const float* Wr       = (const float*)d_in[12];
    const float* att_a    = (const float*)d_in[13];
    const float* gat_bias = (const float*)d_in[14];
    const float* conv1_w  = (const float*)d_in[15];
    const float* conv1_b  = (const float*)d_in[16];
    const float* conv2_w  = (const float*)d_in[17];
    const float* conv2_b  = (const float*)d_in[18];
    const float* Wc       = (const float*)d_in[19];
    const float* bc       = (const float*)d_in[20];
    const float* Wp       = (const float*)d_in[21];
    const float* bp       = (const float*)d_in[22];
    const float* Wh       = (const float*)d_in[23];
    const float* bh       = (const float*)d_in[24];
    const float* Wo       = (const float*)d_in[25];
    const float* bo       = (const float*)d_in[26];
    const float* Wa       = (const float*)d_in[27];
    const float* ba       = (const float*)d_in[28];

    float* out = (float*)d_out;                 // [0,128): out ; [128,400128): alpha
    float* w   = (float*)d_ws;

    size_t off = 0;
    unsigned short* hbuf = (unsigned short*)(w + off); off += (size_t)BN_*H_/2;
    unsigned short* xl   = (unsigned short*)(w + off); off += (size_t)BN_*HC/2;
    unsigned short* xr   = (unsigned short*)(w + off); off += (size_t)BN_*HC/2;
    float* pbuf   = w + off; off += (size_t)ETOT*HEADS;
    float* segsum = w + off; off += (size_t)BN_*HEADS;
    float* nodeo  = w + off; off += (size_t)B_*HC;
    float* c1     = w + off; off += (size_t)16*32*16*16;
    float* c2     = w + off; off += (size_t)16*64*8*8;
    float* tacc   = w + off; off += (size_t)B_*H_;
    unsigned short* Wihb = (unsigned short*)(w + off); off += (size_t)H_*G3/2;
    unsigned short* Whhb = (unsigned short*)(w + off); off += (size_t)H_*G3/2;
    unsigned short* WTb  = (unsigned short*)(w + off); off += (size_t)2*HC*H_/2;
    unsigned short* WnTb = (unsigned short*)(w + off); off += (size_t)H_*32/2;

    k_prep_c1<<<640 + 512, 256, 0, stream>>>(W_ih, W_hh, Wl, Wr, W_nbrs, b_nbrs,
                                             Wihb, Whhb, WTb, WnTb,
                                             segsum, nodeo, tacc,
                                             obs_map, conv1_w, conv1_b, c1);

    k_gruf<<<250, 512, 0, stream>>>(obs, WnTb, Wihb, b_ih, Whhb, b_hh, hbuf);

    k_xlxr_c2<<<625 + 256, 256, 0, stream>>>(hbuf, WTb, xl, xr,
                                             c1, conv2_w, conv2_b, c2);

    k_logits_tb<<<5000 + 512, 256, 0, stream>>>(xl, xr, edges, att_a, pbuf, segsum,
                                                c2, Wc, tacc);

    k_alpha<<<(ETOT*HEADS+255)/256, 256, 0, stream>>>(pbuf, segsum, edges, xl, out+128, nodeo);

    k_head<<<B_, 256, 0, stream>>>(nodeo, gat_bias, tacc, bc, phase,
                                   Wp, bp, Wh, bh, Wo, bo, Wa, ba, out);
}

// Round 16
// 166.667 us; speedup vs baseline: 1.2182x; 1.0153x over previous
//
#include <hip/hip_runtime.h>
#include <hip/hip_bf16.h>
#include <math.h>

#define B_    16
#define N_    1000
#define BN_   16000
#define T_    16
#define FO    16
#define H_    128
#define G3    384       // 3*H
#define HEADS 5
#define HC    640       // heads*H
#define E_    4000
#define EG    64000     // B*E
#define ETOT  80000     // EG + BN self loops
#define P_    8
#define A_    8
#define NEG_SLOPE 0.2f

typedef __attribute__((ext_vector_type(8))) short bf16x8;
typedef __attribute__((ext_vector_type(4))) float f32x4;

__device__ __forceinline__ float bf2f(unsigned short u){ return __uint_as_float(((unsigned)u)<<16); }
__device__ __forceinline__ unsigned short f2bf(float x){
    unsigned u = __float_as_uint(x);
    unsigned r = (u + 0x7FFFu + ((u>>16)&1u)) >> 16;
    return (unsigned short)r;
}
__device__ __forceinline__ unsigned cvtpk(float lo, float hi){
    unsigned r;
    asm volatile("v_cvt_pk_bf16_f32 %0, %1, %2" : "=v"(r) : "v"(lo), "v"(hi));
    return r;
}
__device__ __forceinline__ float rcpf(float x){ return __builtin_amdgcn_rcpf(x); }

// ---------- K1: weight prep + init (blocks 0..639) | conv1 (blocks 640..1151) ----------
__global__ __launch_bounds__(256) void k_prep_c1(
        const float* __restrict__ Wih, const float* __restrict__ Whh,
        const float* __restrict__ Wl, const float* __restrict__ Wr,
        const float* __restrict__ Wn, const float* __restrict__ bn,
        unsigned short* __restrict__ Wihb, unsigned short* __restrict__ Whhb,
        unsigned short* __restrict__ WTb, unsigned short* __restrict__ WnTb,
        float* __restrict__ segsum, float* __restrict__ node_out,
        float* __restrict__ tacc,
        const float* __restrict__ im, const float* __restrict__ w1,
        const float* __restrict__ b1, float* __restrict__ c1out){
    __shared__ float sW[32*4*9];
    int t = threadIdx.x;
    if(blockIdx.x < 640){
        int i = blockIdx.x*256 + t;
        if(i < G3*H_){ Wihb[i] = f2bf(Wih[i]); Whhb[i] = f2bf(Whh[i]); }
        if(i < 2*HC*H_){
            int c = i >> 7, k = i & 127;
            float v = (c < HC) ? Wl[(size_t)k*HC + c] : Wr[(size_t)k*HC + (c-HC)];
            WTb[i] = f2bf(v);
        }
        if(i < H_*32){
            int c = i >> 5, k = i & 31;
            WnTb[i] = (k < FO) ? f2bf(Wn[k*H_ + c])
                     : (k == FO ? f2bf(bn[c]) : (unsigned short)0);
        }
        if(i < BN_*HEADS) segsum[i] = 0.0f;
        if(i < B_*HC) node_out[i] = 0.0f;
        if(i < B_*H_) tacc[i] = 0.0f;
    } else {
        for(int i=t;i<32*4*9;i+=256) sW[i]=w1[i];
        __syncthreads();
        int idx = (blockIdx.x-640)*256 + t;
        int ox = idx & 15, oy = (idx>>4)&15, oc = (idx>>8)&31, b = idx>>13;
        float acc = b1[oc];
        for(int ic=0;ic<4;ic++){
            const float* ip = &im[(size_t)((b*4+ic)*32)*32];
            const float* wp = &sW[(oc*4+ic)*9];
            #pragma unroll
            for(int ky=0;ky<3;ky++){
                int iy = oy*2+ky; if(iy>=32) continue;
                #pragma unroll
                for(int kx=0;kx<3;kx++){
                    int ix = ox*2+kx; if(ix>=32) continue;
                    acc = fmaf(ip[iy*32+ix], wp[ky*3+kx], acc);
                }
            }
        }
        c1out[idx] = fmaxf(acc, 0.f);
    }
}

// ============ K2: fused obs-MLP + gx + GRU + xl/xr GEMM epilogue ============
// 64 nodes/block, 250 blocks. Final h never leaves the block: the xl/xr GEMM
// consumes sH[p]'s MFMA B-fragments directly (same rd[kt] path as Whh*h).
__global__ __launch_bounds__(512,2) void k_gruf(const float* __restrict__ obs,
        const unsigned short* __restrict__ WnTb,
        const unsigned short* __restrict__ Wihb, const float* __restrict__ bih,
        const unsigned short* __restrict__ Whhb, const float* __restrict__ bhh,
        const unsigned short* __restrict__ WTb,
        unsigned short* __restrict__ xl, unsigned short* __restrict__ xr){
    __shared__ unsigned short sX[2*8192];   // [buf][grp(4)][16 nodes][128], swizzled
    __shared__ unsigned short sH[2*8192];
    int t = threadIdx.x;
    int w = t>>6, lane = t&63, lq = lane>>4, lm = lane&15;

    bf16x8 wfi[3][4], wfh[3][4];
    #pragma unroll
    for(int i=0;i<3;i++){
        int row = (8*i + w)*16 + lm;
        #pragma unroll
        for(int kt=0;kt<4;kt++){
            wfi[i][kt] = *(const bf16x8*)&Wihb[row*H_ + kt*32 + lq*8];
            wfh[i][kt] = *(const bf16x8*)&Whhb[row*H_ + kt*32 + lq*8];
        }
    }
    bf16x8 wfn = *(const bf16x8*)&WnTb[(w*16+lm)*32 + lq*8];
    int cb = w*16 + lq*4;
    f32x4 b_r, b_z, bxn, bhn;
    { f32x4 t1=*(const f32x4*)&bih[cb],     t2=*(const f32x4*)&bhh[cb];     b_r=t1+t2; }
    { f32x4 t1=*(const f32x4*)&bih[128+cb], t2=*(const f32x4*)&bhh[128+cb]; b_z=t1+t2; }
    bxn = *(const f32x4*)&bih[256+cb];
    bhn = *(const f32x4*)&bhh[256+cb];

    int rd[4];
    #pragma unroll
    for(int kt=0;kt<4;kt++) rd[kt] = lm*128 + (((4*kt+lq)^(lm&7))<<3);
    const int wrt = lm*128 + (((2*w + (lq>>1))^(lm&7))<<3) + ((lq&1)<<2);

    int nodeBase = blockIdx.x*64;
    const float* obp0 = &obs[(size_t)(nodeBase + lm)*256 + lq*8];

    for(int i=t;i<4096;i+=512) ((unsigned*)sH)[i] = 0u;   // zero sH buf 0 (16KB)
    float ho[4][4] = {{0.f,0.f,0.f,0.f},{0.f,0.f,0.f,0.f},
                      {0.f,0.f,0.f,0.f},{0.f,0.f,0.f,0.f}};

    float4 oA[4], oB[4];
    if(lq < 2){
        #pragma unroll
        for(int g=0; g<4; g++){
            const float* q = obp0 + (size_t)g*16*256;
            oA[g] = *(const float4*)(q);    oB[g] = *(const float4*)(q+4);
        }
    }
    #pragma unroll
    for(int g=0; g<4; g++){
        bf16x8 ob = (bf16x8){0,0,0,0,0,0,0,0};
        if(lq < 2){
            union { uint4 u; bf16x8 v; } cv;
            cv.u = make_uint4(cvtpk(oA[g].x,oA[g].y), cvtpk(oA[g].z,oA[g].w),
                              cvtpk(oB[g].x,oB[g].y), cvtpk(oB[g].z,oB[g].w));
            ob = cv.v;
        } else if(lq == 2){
            ob[0] = (short)0x3F80;          // k==16 -> bias row of WnT
        }
        f32x4 xa = (f32x4){0.f,0.f,0.f,0.f};
        xa = __builtin_amdgcn_mfma_f32_16x16x32_bf16(wfn, ob, xa, 0,0,0);
        unsigned u0 = cvtpk(fmaxf(xa[0],0.f), fmaxf(xa[1],0.f));
        unsigned u1 = cvtpk(fmaxf(xa[2],0.f), fmaxf(xa[3],0.f));
        *(uint2*)&sX[g*2048 + wrt] = make_uint2(u0,u1);
    }
    __syncthreads();

    int p = 0;
    #pragma unroll 1
    for(int s=0; s<T_; s++){
        if(s < T_-1 && lq < 2){
            #pragma unroll
            for(int g=0; g<4; g++){
                const float* q = obp0 + (size_t)g*16*256 + (s+1)*16;
                oA[g] = *(const float4*)(q);    oB[g] = *(const float4*)(q+4);
            }
        }
        #pragma unroll
        for(int g=0; g<4; g++){
            int base = p*8192 + g*2048;
            bf16x8 xb[4], hb[4];
            #pragma unroll
            for(int kt=0;kt<4;kt++){
                xb[kt] = *(const bf16x8*)&sX[base + rd[kt]];
                hb[kt] = *(const bf16x8*)&sH[base + rd[kt]];
            }
            f32x4 ar = b_r, az = b_z, axi = bxn, ahh = bhn;   // bias-in-C
            #pragma unroll
            for(int kt=0;kt<4;kt++){
                ar  = __builtin_amdgcn_mfma_f32_16x16x32_bf16(wfi[0][kt], xb[kt], ar, 0,0,0);
                az  = __builtin_amdgcn_mfma_f32_16x16x32_bf16(wfi[1][kt], xb[kt], az, 0,0,0);
                axi = __builtin_amdgcn_mfma_f32_16x16x32_bf16(wfi[2][kt], xb[kt], axi, 0,0,0);
                ar  = __builtin_amdgcn_mfma_f32_16x16x32_bf16(wfh[0][kt], hb[kt], ar, 0,0,0);
                az  = __builtin_amdgcn_mfma_f32_16x16x32_bf16(wfh[1][kt], hb[kt], az, 0,0,0);
                ahh = __builtin_amdgcn_mfma_f32_16x16x32_bf16(wfh[2][kt], hb[kt], ahh, 0,0,0);
            }
            #pragma unroll
            for(int v=0;v<4;v++){
                float er = __expf(-ar[v]);
                float r  = rcpf(1.f + er);
                float ez = __expf(-az[v]);
                float z  = rcpf(1.f + ez);
                float xn = fmaf(r, ahh[v], axi[v]);
                float en = __expf(-2.f*xn);
                float nn = fmaf(2.f, rcpf(1.f + en), -1.f);
                ho[g][v] = nn + z*(ho[g][v] - nn);
            }
            unsigned u0 = cvtpk(ho[g][0], ho[g][1]);
            unsigned u1 = cvtpk(ho[g][2], ho[g][3]);
            *(uint2*)&sH[(p^1)*8192 + g*2048 + wrt] = make_uint2(u0,u1);
        }
        if(s < T_-1){
            #pragma unroll
            for(int g=0; g<4; g++){
                bf16x8 ob = (bf16x8){0,0,0,0,0,0,0,0};
                if(lq < 2){
                    union { uint4 u; bf16x8 v; } cv;
                    cv.u = make_uint4(cvtpk(oA[g].x,oA[g].y), cvtpk(oA[g].z,oA[g].w),
                                      cvtpk(oB[g].x,oB[g].y), cvtpk(oB[g].z,oB[g].w));
                    ob = cv.v;
                } else if(lq == 2){
                    ob[0] = (short)0x3F80;
                }
                f32x4 xa = (f32x4){0.f,0.f,0.f,0.f};
                xa = __builtin_amdgcn_mfma_f32_16x16x32_bf16(wfn, ob, xa, 0,0,0);
                unsigned u0 = cvtpk(fmaxf(xa[0],0.f), fmaxf(xa[1],0.f));
                unsigned u1 = cvtpk(fmaxf(xa[2],0.f), fmaxf(xa[3],0.f));
                *(uint2*)&sX[(p^1)*8192 + g*2048 + wrt] = make_uint2(u0,u1);
            }
        }
        __syncthreads();
        p ^= 1;
    }

    // ---- epilogue: xl|xr = h @ [Wl|Wr] directly from sH[p] ----
    // wave w owns col tiles {w, w+8, ..., w+72}; h fragments cached in regs.
    bf16x8 hba[4][4];
    #pragma unroll
    for(int g=0;g<4;g++){
        #pragma unroll
        for(int kt=0;kt<4;kt++)
            hba[g][kt] = *(const bf16x8*)&sH[p*8192 + g*2048 + rd[kt]];
    }
    #pragma unroll 1
    for(int tt=0; tt<10; tt++){
        int tile = w + tt*8;              // 0..79 over [xl|xr] cols
        int row = tile*16 + lm;           // WT row = out col
        bf16x8 wf[4];
        #pragma unroll
        for(int kt=0;kt<4;kt++)
            wf[kt] = *(const bf16x8*)&WTb[(size_t)row*H_ + kt*32 + lq*8];
        #pragma unroll
        for(int g=0;g<4;g++){
            f32x4 acc = (f32x4){0.f,0.f,0.f,0.f};
            #pragma unroll
            for(int kt=0;kt<4;kt++)
                acc = __builtin_amdgcn_mfma_f32_16x16x32_bf16(wf[kt], hba[g][kt], acc, 0,0,0);
            int node = nodeBase + g*16 + lm;
            int col = tile*16 + lq*4;
            ushort4 o;
            o.x=f2bf(acc[0]); o.y=f2bf(acc[1]); o.z=f2bf(acc[2]); o.w=f2bf(acc[3]);
            if(col < HC) *(ushort4*)&xl[(size_t)node*HC + col] = o;
            else         *(ushort4*)&xr[(size_t)node*HC + (col-HC)] = o;
        }
    }
}

// ---------------- K3: conv2 32->64, 16x16 -> 8x8 (standalone, 256 blocks) ------------
__global__ __launch_bounds__(256) void k_conv2(const float* __restrict__ c1,
        const float* __restrict__ w, const float* __restrict__ bias, float* __restrict__ outp){
    int idx = blockIdx.x*256 + threadIdx.x;
    if(idx >= 16*64*8*8) return;
    int ox = idx & 7, oy = (idx>>3)&7, oc = (idx>>6)&63, b = idx>>12;
    float acc = bias[oc];
    for(int ic=0;ic<32;ic++){
        const float* ip = &c1[(size_t)((b*32+ic)*16)*16];
        const float* wp = &w[(oc*32+ic)*9];
        #pragma unroll
        for(int ky=0;ky<3;ky++){
            int iy = oy*2+ky; if(iy>=16) continue;
            #pragma unroll
            for(int kx=0;kx<3;kx++){
                int ix = ox*2+kx; if(ix>=16) continue;
                acc = fmaf(ip[iy*16+ix], wp[ky*3+kx], acc);
            }
        }
    }
    outp[idx] = fmaxf(acc, 0.f);
}

// ---------------- edge src/dst helper ----------------
__device__ __forceinline__ void edge_sd(int e, const int* __restrict__ edges, int* src, int* dst){
    if(e < EG){
        int b = e / E_, j = e - b*E_;
        *src = edges[(b*2+0)*E_ + j] + b*N_;
        *dst = edges[(b*2+1)*E_ + j] + b*N_;
    } else { *src = *dst = e - EG; }
}

// ---------- K4: logits+exp+segsum, XCD-swizzled (blocks 0..4999) | temb (5000..5511) ----
__global__ __launch_bounds__(256) void k_logits_tb(const unsigned short* __restrict__ xl,
        const unsigned short* __restrict__ xr, const int* __restrict__ edges,
        const float* __restrict__ atta, float* __restrict__ pbuf,
        float* __restrict__ segsum,
        const float* __restrict__ c2, const float* __restrict__ Wc,
        float* __restrict__ tacc){
    __shared__ float sC[128];
    int t = threadIdx.x;
    if(blockIdx.x < 5000){
        int lb = (blockIdx.x & 7)*625 + (blockIdx.x >> 3);
        int lane = t & 63, w = t >> 6;
        float am[8], a4[8];
        #pragma unroll
        for(int j=0;j<8;j++) am[j] = atta[lane*8+j];
        #pragma unroll
        for(int j=0;j<8;j++) a4[j] = (lane<16) ? atta[512+lane*8+j] : 0.f;

        int e0 = lb*16 + w*4;
        int srcs[4], dsts[4];
        #pragma unroll
        for(int i=0;i<4;i++) edge_sd(e0+i, edges, &srcs[i], &dsts[i]);
        #pragma unroll
        for(int i=0;i<4;i++){
            const unsigned short* xls = &xl[(size_t)srcs[i]*HC];
            const unsigned short* xrd = &xr[(size_t)dsts[i]*HC];
            uint4 ul = *(const uint4*)&xls[lane*8];
            uint4 ur = *(const uint4*)&xrd[lane*8];
            uint4 tl = make_uint4(0,0,0,0), tr = make_uint4(0,0,0,0);
            if(lane < 16){
                tl = *(const uint4*)&xls[512+lane*8];
                tr = *(const uint4*)&xrd[512+lane*8];
            }
            float pm = 0.f, p4 = 0.f;
            {
                unsigned pl[4] = {ul.x,ul.y,ul.z,ul.w};
                unsigned pr[4] = {ur.x,ur.y,ur.z,ur.w};
                #pragma unroll
                for(int q=0;q<4;q++){
                    float s0 = bf2f((unsigned short)(pl[q]&0xFFFFu)) + bf2f((unsigned short)(pr[q]&0xFFFFu));
                    float s1 = bf2f((unsigned short)(pl[q]>>16))     + bf2f((unsigned short)(pr[q]>>16));
                    s0 = s0 > 0.f ? s0 : NEG_SLOPE*s0;
                    s1 = s1 > 0.f ? s1 : NEG_SLOPE*s1;
                    pm = fmaf(s0, am[2*q],   pm);
                    pm = fmaf(s1, am[2*q+1], pm);
                }
            }
            {
                unsigned ql[4] = {tl.x,tl.y,tl.z,tl.w};
                unsigned qr[4] = {tr.x,tr.y,tr.z,tr.w};
                #pragma unroll
                for(int q=0;q<4;q++){
                    float s0 = bf2f((unsigned short)(ql[q]&0xFFFFu)) + bf2f((unsigned short)(qr[q]&0xFFFFu));
                    float s1 = bf2f((unsigned short)(ql[q]>>16))     + bf2f((unsigned short)(qr[q]>>16));
                    s0 = s0 > 0.f ? s0 : NEG_SLOPE*s0;
                    s1 = s1 > 0.f ? s1 : NEG_SLOPE*s1;
                    p4 = fmaf(s0, a4[2*q],   p4);
                    p4 = fmaf(s1, a4[2*q+1], p4);
                }
            }
            #pragma unroll
            for(int off=1; off<16; off<<=1){
                pm += __shfl_xor(pm, off);
                p4 += __shfl_xor(p4, off);
            }
            if((lane & 15) == 0){
                int hh = lane >> 4;
                float p = __expf(pm);
                pbuf[(size_t)(e0+i)*HEADS + hh] = p;
                atomicAdd(&segsum[dsts[i]*HEADS + hh], p);
            }
            if(lane == 8){
                float p = __expf(p4);
                pbuf[(size_t)(e0+i)*HEADS + 4] = p;
                atomicAdd(&segsum[dsts[i]*HEADS + 4], p);
            }
        }
    } else {
        int bb = blockIdx.x - 5000;
        int b = bb >> 5, ks = bb & 31;
        int k0 = ks*128;
        if(t < 128) sC[t] = c2[(size_t)b*4096 + k0 + t];
        __syncthreads();
        int j = t & 127, sub = t >> 7;
        const float* wp = &Wc[(size_t)(k0 + sub*64)*H_ + j];
        const float* cp = &sC[sub*64];
        float a0=0.f, a1=0.f, a2=0.f, a3=0.f;
        #pragma unroll
        for(int kk=0; kk<64; kk+=4){
            a0 = fmaf(cp[kk+0], wp[(size_t)(kk+0)*H_], a0);
            a1 = fmaf(cp[kk+1], wp[(size_t)(kk+1)*H_], a1);
            a2 = fmaf(cp[kk+2], wp[(size_t)(kk+2)*H_], a2);
            a3 = fmaf(cp[kk+3], wp[(size_t)(kk+3)*H_], a3);
        }
        atomicAdd(&tacc[b*H_+j], (a0+a1)+(a2+a3));
    }
}

// ---------------- K5: alpha = p/segsum + wave-cooperative ego accumulation ----------
__global__ void k_alpha(const float* __restrict__ pbuf, const float* __restrict__ segsum,
                        const int* __restrict__ edges, const unsigned short* __restrict__ xl,
                        float* __restrict__ out_alpha, float* __restrict__ node_out){
    int idx = blockIdx.x*256 + threadIdx.x;
    int lane = threadIdx.x & 63;
    bool valid = idx < ETOT*HEADS;
    int e = 0, hh = 0, src = 0, dst = 0;
    float a = 0.f;
    bool ego = false;
    if(valid){
        e = idx / HEADS; hh = idx - e*HEADS;
        edge_sd(e, edges, &src, &dst);
        a = pbuf[idx] / segsum[dst*HEADS + hh];
        out_alpha[idx] = a;
        ego = (dst % N_) == 0;
    }
    unsigned long long m = __ballot(ego);
    while(m){
        int l = __ffsll((unsigned long long)m) - 1;
        m &= (m - 1);
        float aa = __shfl(a, l);
        int ss = __shfl(src, l), dd = __shfl(dst, l), hq = __shfl(hh, l);
        int b = dd / N_;
        unsigned u = *(const unsigned*)&xl[(size_t)ss*HC + hq*H_ + lane*2];
        float* no = &node_out[b*HC + hq*H_ + lane*2];
        atomicAdd(no,     aa * bf2f((unsigned short)(u & 0xFFFFu)));
        atomicAdd(no + 1, aa * bf2f((unsigned short)(u >> 16)));
    }
}

// ---------------- K6: head, 16 blocks (one per sample) ----------------
__global__ __launch_bounds__(256) void k_head(const float* __restrict__ node_out,
        const float* __restrict__ gat_bias, const float* __restrict__ tacc,
        const float* __restrict__ bc, const float* __restrict__ phase,
        const float* __restrict__ Wp, const float* __restrict__ bp,
        const float* __restrict__ Wh, const float* __restrict__ bh,
        const float* __restrict__ Wo, const float* __restrict__ bo,
        const float* __restrict__ Wa, const float* __restrict__ ba,
        float* __restrict__ out){
    __shared__ float sF[268];
    __shared__ float sHid[128];
    int t = threadIdx.x;
    int b = blockIdx.x;
    if(t < 128){
        float s=0.f;
        #pragma unroll
        for(int hh=0;hh<HEADS;hh++) s += node_out[b*HC + hh*H_ + t];
        sF[t] = s*(1.0f/HEADS) + gat_bias[t];
    } else {
        int c = t - 128;
        sF[128+c] = fmaxf(tacc[b*H_ + c] + bc[c], 0.f);
    }
    if(t < P_){
        float s=bp[t];
        #pragma unroll
        for(int q=0;q<P_;q++) s = fmaf(phase[b*P_+q], Wp[q*P_+t], s);
        sF[256+t] = fmaxf(s, 0.f);
    }
    __syncthreads();
    if(t < 128){
        float s=bh[t];
        for(int k=0;k<2*H_+P_;k++) s = fmaf(sF[k], Wh[k*H_+t], s);
        sHid[t]=fmaxf(s,0.f);
    }
    __syncthreads();
    if(t < A_){
        float v=bo[0], ad=ba[t];
        for(int k=0;k<H_;k++){ float hv=sHid[k]; v = fmaf(hv,Wo[k],v); ad = fmaf(hv,Wa[k*A_+t],ad); }
        float m = ad;
        m += __shfl_xor(m,1); m += __shfl_xor(m,2); m += __shfl_xor(m,4);
        m *= 0.125f;
        out[b*A_+t] = v + ad - m;
    }
}

extern "C" void kernel_launch(void* const* d_in, const int* in_sizes, int n_in,
                              void* d_out, int out_size, void* d_ws, size_t ws_size,
                              hipStream_t stream) {
    (void)in_sizes; (void)n_in; (void)out_size; (void)ws_size;
    const float* obs      = (const float*)d_in[0];
    const float* phase    = (const float*)d_in[1];
    const float* obs_map  = (const float*)d_in[2];
    const int*   edges    = (const int*)  d_in[3];
    const float* W_nbrs   = (const float*)d_in[5];
    const float* b_nbrs   = (const float*)d_in[6];
    const float* W_ih     = (const float*)d_in[7];
    const float* W_hh     = (const float*)d_in[8];
    const float* b_ih     = (const float*)d_in[9];
    const float* b_hh     = (const float*)d_in[10];
    const float* Wl       = (const float*)d_in[11];
    const float* Wr       = (const float*)d_in[12];
    const float* att_a    = (const float*)d_in[13];
    const float* gat_bias = (const float*)d_in[14];
    const float* conv1_w  = (const float*)d_in[15];
    const float* conv1_b  = (const float*)d_in[16];
    const float* conv2_w  = (const float*)d_in[17];
    const float* conv2_b  = (const float*)d_in[18];
    const float* Wc       = (const float*)d_in[19];
    const float* bc       = (const float*)d_in[20];
    const float* Wp       = (const float*)d_in[21];
    const float* bp       = (const float*)d_in[22];
    const float* Wh       = (const float*)d_in[23];
    const float* bh       = (const float*)d_in[24];
    const float* Wo       = (const float*)d_in[25];
    const float* bo       = (const float*)d_in[26];
    const float* Wa       = (const float*)d_in[27];
    const float* ba       = (const float*)d_in[28];

    float* out = (float*)d_out;                 // [0,128): out ; [128,400128): alpha
    float* w   = (float*)d_ws;

    size_t off = 0;
    unsigned short* xl   = (unsigned short*)(w + off); off += (size_t)BN_*HC/2;
    unsigned short* xr   = (unsigned short*)(w + off); off += (size_t)BN_*HC/2;
    float* pbuf   = w + off; off += (size_t)ETOT*HEADS;
    float* segsum = w + off; off += (size_t)BN_*HEADS;
    float* nodeo  = w + off; off += (size_t)B_*HC;
    float* c1     = w + off; off += (size_t)16*32*16*16;
    float* c2     = w + off; off += (size_t)16*64*8*8;
    float* tacc   = w + off; off += (size_t)B_*H_;
    unsigned short* Wihb = (unsigned short*)(w + off); off += (size_t)H_*G3/2;
    unsigned short* Whhb = (unsigned short*)(w + off); off += (size_t)H_*G3/2;
    unsigned short* WTb  = (unsigned short*)(w + off); off += (size_t)2*HC*H_/2;
    unsigned short* WnTb = (unsigned short*)(w + off); off += (size_t)H_*32/2;

    k_prep_c1<<<640 + 512, 256, 0, stream>>>(W_ih, W_hh, Wl, Wr, W_nbrs, b_nbrs,
                                             Wihb, Whhb, WTb, WnTb,
                                             segsum, nodeo, tacc,
                                             obs_map, conv1_w, conv1_b, c1);

    k_gruf<<<250, 512, 0, stream>>>(obs, WnTb, Wihb, b_ih, Whhb, b_hh, WTb, xl, xr);

    k_conv2<<<(16*64*8*8)/256, 256, 0, stream>>>(c1, conv2_w, conv2_b, c2);

    k_logits_tb<<<5000 + 512, 256, 0, stream>>>(xl, xr, edges, att_a, pbuf, segsum,
                                                c2, Wc, tacc);

    k_alpha<<<(ETOT*HEADS+255)/256, 256, 0, stream>>>(pbuf, segsum, edges, xl, out+128, nodeo);

    k_head<<<B_, 256, 0, stream>>>(nodeo, gat_bias, tacc, bc, phase,
                                   Wp, bp, Wh, bh, Wo, bo, Wa, ba, out);
}

// Round 17
// 166.531 us; speedup vs baseline: 1.2192x; 1.0008x over previous
//
#include <hip/hip_runtime.h>
#include <hip/hip_bf16.h>
#include <math.h>

#define B_    16
#define N_    1000
#define BN_   16000
#define T_    16
#define FO    16
#define H_    128
#define G3    384       // 3*H
#define HEADS 5
#define HC    640       // heads*H
#define E_    4000
#define EG    64000     // B*E
#define ETOT  80000     // EG + BN self loops
#define P_    8
#define A_    8
#define NEG_SLOPE 0.2f

typedef __attribute__((ext_vector_type(8))) short bf16x8;
typedef __attribute__((ext_vector_type(4))) float f32x4;

__device__ __forceinline__ float bf2f(unsigned short u){ return __uint_as_float(((unsigned)u)<<16); }
__device__ __forceinline__ unsigned short f2bf(float x){
    unsigned u = __float_as_uint(x);
    unsigned r = (u + 0x7FFFu + ((u>>16)&1u)) >> 16;
    return (unsigned short)r;
}
__device__ __forceinline__ unsigned cvtpk(float lo, float hi){
    unsigned r;
    asm volatile("v_cvt_pk_bf16_f32 %0, %1, %2" : "=v"(r) : "v"(lo), "v"(hi));
    return r;
}
__device__ __forceinline__ float rcpf(float x){ return __builtin_amdgcn_rcpf(x); }

// ---------- K1: weight prep + init (blocks 0..639) | conv1 (blocks 640..1151) ----------
__global__ __launch_bounds__(256) void k_prep_c1(
        const float* __restrict__ Wih, const float* __restrict__ Whh,
        const float* __restrict__ Wl, const float* __restrict__ Wr,
        const float* __restrict__ Wn, const float* __restrict__ bn,
        unsigned short* __restrict__ Wihb, unsigned short* __restrict__ Whhb,
        unsigned short* __restrict__ WTb, unsigned short* __restrict__ WnTb,
        float* __restrict__ segsum, float* __restrict__ node_out,
        float* __restrict__ tacc,
        const float* __restrict__ im, const float* __restrict__ w1,
        const float* __restrict__ b1, float* __restrict__ c1out){
    __shared__ float sW[32*4*9];
    int t = threadIdx.x;
    if(blockIdx.x < 640){
        int i = blockIdx.x*256 + t;
        if(i < G3*H_){ Wihb[i] = f2bf(Wih[i]); Whhb[i] = f2bf(Whh[i]); }
        if(i < 2*HC*H_){
            int c = i >> 7, k = i & 127;
            float v = (c < HC) ? Wl[(size_t)k*HC + c] : Wr[(size_t)k*HC + (c-HC)];
            WTb[i] = f2bf(v);
        }
        if(i < H_*32){
            int c = i >> 5, k = i & 31;
            WnTb[i] = (k < FO) ? f2bf(Wn[k*H_ + c])
                     : (k == FO ? f2bf(bn[c]) : (unsigned short)0);
        }
        if(i < BN_*HEADS) segsum[i] = 0.0f;
        if(i < B_*HC) node_out[i] = 0.0f;
        if(i < B_*H_) tacc[i] = 0.0f;
    } else {
        for(int i=t;i<32*4*9;i+=256) sW[i]=w1[i];
        __syncthreads();
        int idx = (blockIdx.x-640)*256 + t;
        int ox = idx & 15, oy = (idx>>4)&15, oc = (idx>>8)&31, b = idx>>13;
        float acc = b1[oc];
        for(int ic=0;ic<4;ic++){
            const float* ip = &im[(size_t)((b*4+ic)*32)*32];
            const float* wp = &sW[(oc*4+ic)*9];
            #pragma unroll
            for(int ky=0;ky<3;ky++){
                int iy = oy*2+ky; if(iy>=32) continue;
                #pragma unroll
                for(int kx=0;kx<3;kx++){
                    int ix = ox*2+kx; if(ix>=32) continue;
                    acc = fmaf(ip[iy*32+ix], wp[ky*3+kx], acc);
                }
            }
        }
        c1out[idx] = fmaxf(acc, 0.f);
    }
}

// ============ K2: fused obs-MLP + gx + GRU + xl/xr GEMM epilogue (pipelined) ============
__global__ __launch_bounds__(512,2) void k_gruf(const float* __restrict__ obs,
        const unsigned short* __restrict__ WnTb,
        const unsigned short* __restrict__ Wihb, const float* __restrict__ bih,
        const unsigned short* __restrict__ Whhb, const float* __restrict__ bhh,
        const unsigned short* __restrict__ WTb,
        unsigned short* __restrict__ xl, unsigned short* __restrict__ xr){
    __shared__ unsigned short sX[2*8192];   // [buf][grp(4)][16 nodes][128], swizzled
    __shared__ unsigned short sH[2*8192];
    int t = threadIdx.x;
    int w = t>>6, lane = t&63, lq = lane>>4, lm = lane&15;

    bf16x8 wfi[3][4], wfh[3][4];
    #pragma unroll
    for(int i=0;i<3;i++){
        int row = (8*i + w)*16 + lm;
        #pragma unroll
        for(int kt=0;kt<4;kt++){
            wfi[i][kt] = *(const bf16x8*)&Wihb[row*H_ + kt*32 + lq*8];
            wfh[i][kt] = *(const bf16x8*)&Whhb[row*H_ + kt*32 + lq*8];
        }
    }
    bf16x8 wfn = *(const bf16x8*)&WnTb[(w*16+lm)*32 + lq*8];
    int cb = w*16 + lq*4;
    f32x4 b_r, b_z, bxn, bhn;
    { f32x4 t1=*(const f32x4*)&bih[cb],     t2=*(const f32x4*)&bhh[cb];     b_r=t1+t2; }
    { f32x4 t1=*(const f32x4*)&bih[128+cb], t2=*(const f32x4*)&bhh[128+cb]; b_z=t1+t2; }
    bxn = *(const f32x4*)&bih[256+cb];
    bhn = *(const f32x4*)&bhh[256+cb];

    int rd[4];
    #pragma unroll
    for(int kt=0;kt<4;kt++) rd[kt] = lm*128 + (((4*kt+lq)^(lm&7))<<3);
    const int wrt = lm*128 + (((2*w + (lq>>1))^(lm&7))<<3) + ((lq&1)<<2);

    int nodeBase = blockIdx.x*64;
    const float* obp0 = &obs[(size_t)(nodeBase + lm)*256 + lq*8];

    for(int i=t;i<4096;i+=512) ((unsigned*)sH)[i] = 0u;   // zero sH buf 0 (16KB)
    float ho[4][4] = {{0.f,0.f,0.f,0.f},{0.f,0.f,0.f,0.f},
                      {0.f,0.f,0.f,0.f},{0.f,0.f,0.f,0.f}};

    float4 oA[4], oB[4];
    if(lq < 2){
        #pragma unroll
        for(int g=0; g<4; g++){
            const float* q = obp0 + (size_t)g*16*256;
            oA[g] = *(const float4*)(q);    oB[g] = *(const float4*)(q+4);
        }
    }
    #pragma unroll
    for(int g=0; g<4; g++){
        bf16x8 ob = (bf16x8){0,0,0,0,0,0,0,0};
        if(lq < 2){
            union { uint4 u; bf16x8 v; } cv;
            cv.u = make_uint4(cvtpk(oA[g].x,oA[g].y), cvtpk(oA[g].z,oA[g].w),
                              cvtpk(oB[g].x,oB[g].y), cvtpk(oB[g].z,oB[g].w));
            ob = cv.v;
        } else if(lq == 2){
            ob[0] = (short)0x3F80;          // k==16 -> bias row of WnT
        }
        f32x4 xa = (f32x4){0.f,0.f,0.f,0.f};
        xa = __builtin_amdgcn_mfma_f32_16x16x32_bf16(wfn, ob, xa, 0,0,0);
        unsigned u0 = cvtpk(fmaxf(xa[0],0.f), fmaxf(xa[1],0.f));
        unsigned u1 = cvtpk(fmaxf(xa[2],0.f), fmaxf(xa[3],0.f));
        *(uint2*)&sX[g*2048 + wrt] = make_uint2(u0,u1);
    }
    __syncthreads();

    int p = 0;
    #pragma unroll 1
    for(int s=0; s<T_; s++){
        if(s < T_-1 && lq < 2){
            #pragma unroll
            for(int g=0; g<4; g++){
                const float* q = obp0 + (size_t)g*16*256 + (s+1)*16;
                oA[g] = *(const float4*)(q);    oB[g] = *(const float4*)(q+4);
            }
        }
        #pragma unroll
        for(int g=0; g<4; g++){
            int base = p*8192 + g*2048;
            bf16x8 xb[4], hb[4];
            #pragma unroll
            for(int kt=0;kt<4;kt++){
                xb[kt] = *(const bf16x8*)&sX[base + rd[kt]];
                hb[kt] = *(const bf16x8*)&sH[base + rd[kt]];
            }
            f32x4 ar = b_r, az = b_z, axi = bxn, ahh = bhn;   // bias-in-C
            #pragma unroll
            for(int kt=0;kt<4;kt++){
                ar  = __builtin_amdgcn_mfma_f32_16x16x32_bf16(wfi[0][kt], xb[kt], ar, 0,0,0);
                az  = __builtin_amdgcn_mfma_f32_16x16x32_bf16(wfi[1][kt], xb[kt], az, 0,0,0);
                axi = __builtin_amdgcn_mfma_f32_16x16x32_bf16(wfi[2][kt], xb[kt], axi, 0,0,0);
                ar  = __builtin_amdgcn_mfma_f32_16x16x32_bf16(wfh[0][kt], hb[kt], ar, 0,0,0);
                az  = __builtin_amdgcn_mfma_f32_16x16x32_bf16(wfh[1][kt], hb[kt], az, 0,0,0);
                ahh = __builtin_amdgcn_mfma_f32_16x16x32_bf16(wfh[2][kt], hb[kt], ahh, 0,0,0);
            }
            #pragma unroll
            for(int v=0;v<4;v++){
                float er = __expf(-ar[v]);
                float r  = rcpf(1.f + er);
                float ez = __expf(-az[v]);
                float z  = rcpf(1.f + ez);
                float xn = fmaf(r, ahh[v], axi[v]);
                float en = __expf(-2.f*xn);
                float nn = fmaf(2.f, rcpf(1.f + en), -1.f);
                ho[g][v] = nn + z*(ho[g][v] - nn);
            }
            unsigned u0 = cvtpk(ho[g][0], ho[g][1]);
            unsigned u1 = cvtpk(ho[g][2], ho[g][3]);
            *(uint2*)&sH[(p^1)*8192 + g*2048 + wrt] = make_uint2(u0,u1);
        }
        if(s < T_-1){
            #pragma unroll
            for(int g=0; g<4; g++){
                bf16x8 ob = (bf16x8){0,0,0,0,0,0,0,0};
                if(lq < 2){
                    union { uint4 u; bf16x8 v; } cv;
                    cv.u = make_uint4(cvtpk(oA[g].x,oA[g].y), cvtpk(oA[g].z,oA[g].w),
                                      cvtpk(oB[g].x,oB[g].y), cvtpk(oB[g].z,oB[g].w));
                    ob = cv.v;
                } else if(lq == 2){
                    ob[0] = (short)0x3F80;
                }
                f32x4 xa = (f32x4){0.f,0.f,0.f,0.f};
                xa = __builtin_amdgcn_mfma_f32_16x16x32_bf16(wfn, ob, xa, 0,0,0);
                unsigned u0 = cvtpk(fmaxf(xa[0],0.f), fmaxf(xa[1],0.f));
                unsigned u1 = cvtpk(fmaxf(xa[2],0.f), fmaxf(xa[3],0.f));
                *(uint2*)&sX[(p^1)*8192 + g*2048 + wrt] = make_uint2(u0,u1);
            }
        }
        __syncthreads();
        p ^= 1;
    }

    // ---- epilogue: xl|xr = h @ [Wl|Wr] from sH[p], WT loads double-buffered ----
    // issue tt=0 WT loads first (overlap with hba LDS reads)
    bf16x8 wfA[4], wfB[4];
    {
        int row = w*16 + lm;
        #pragma unroll
        for(int kt=0;kt<4;kt++)
            wfA[kt] = *(const bf16x8*)&WTb[(size_t)row*H_ + kt*32 + lq*8];
    }
    bf16x8 hba[4][4];
    #pragma unroll
    for(int g=0;g<4;g++){
        #pragma unroll
        for(int kt=0;kt<4;kt++)
            hba[g][kt] = *(const bf16x8*)&sH[p*8192 + g*2048 + rd[kt]];
    }
    #pragma unroll 1
    for(int tt=0; tt<10; tt++){
        if(tt < 9){
            int row = (w + (tt+1)*8)*16 + lm;     // prefetch next tile's WT rows
            #pragma unroll
            for(int kt=0;kt<4;kt++)
                wfB[kt] = *(const bf16x8*)&WTb[(size_t)row*H_ + kt*32 + lq*8];
        }
        int tile = w + tt*8;
        #pragma unroll
        for(int g=0;g<4;g++){
            f32x4 acc = (f32x4){0.f,0.f,0.f,0.f};
            #pragma unroll
            for(int kt=0;kt<4;kt++)
                acc = __builtin_amdgcn_mfma_f32_16x16x32_bf16(wfA[kt], hba[g][kt], acc, 0,0,0);
            int node = nodeBase + g*16 + lm;
            int col = tile*16 + lq*4;
            ushort4 o;
            o.x=f2bf(acc[0]); o.y=f2bf(acc[1]); o.z=f2bf(acc[2]); o.w=f2bf(acc[3]);
            if(col < HC) *(ushort4*)&xl[(size_t)node*HC + col] = o;
            else         *(ushort4*)&xr[(size_t)node*HC + (col-HC)] = o;
        }
        #pragma unroll
        for(int kt=0;kt<4;kt++) wfA[kt] = wfB[kt];
    }
}

// ---------------- K3: conv2 32->64, 16x16 -> 8x8 (standalone, 256 blocks) ------------
__global__ __launch_bounds__(256) void k_conv2(const float* __restrict__ c1,
        const float* __restrict__ w, const float* __restrict__ bias, float* __restrict__ outp){
    int idx = blockIdx.x*256 + threadIdx.x;
    if(idx >= 16*64*8*8) return;
    int ox = idx & 7, oy = (idx>>3)&7, oc = (idx>>6)&63, b = idx>>12;
    float acc = bias[oc];
    for(int ic=0;ic<32;ic++){
        const float* ip = &c1[(size_t)((b*32+ic)*16)*16];
        const float* wp = &w[(oc*32+ic)*9];
        #pragma unroll
        for(int ky=0;ky<3;ky++){
            int iy = oy*2+ky; if(iy>=16) continue;
            #pragma unroll
            for(int kx=0;kx<3;kx++){
                int ix = ox*2+kx; if(ix>=16) continue;
                acc = fmaf(ip[iy*16+ix], wp[ky*3+kx], acc);
            }
        }
    }
    outp[idx] = fmaxf(acc, 0.f);
}

// ---------------- edge src/dst helper ----------------
__device__ __forceinline__ void edge_sd(int e, const int* __restrict__ edges, int* src, int* dst){
    if(e < EG){
        int b = e / E_, j = e - b*E_;
        *src = edges[(b*2+0)*E_ + j] + b*N_;
        *dst = edges[(b*2+1)*E_ + j] + b*N_;
    } else { *src = *dst = e - EG; }
}

// ---------- K4: logits+exp+segsum, XCD-swizzled (blocks 0..4999) | temb (5000..5511) ----
__global__ __launch_bounds__(256) void k_logits_tb(const unsigned short* __restrict__ xl,
        const unsigned short* __restrict__ xr, const int* __restrict__ edges,
        const float* __restrict__ atta, float* __restrict__ pbuf,
        float* __restrict__ segsum,
        const float* __restrict__ c2, const float* __restrict__ Wc,
        float* __restrict__ tacc){
    __shared__ float sC[128];
    int t = threadIdx.x;
    if(blockIdx.x < 5000){
        int lb = (blockIdx.x & 7)*625 + (blockIdx.x >> 3);
        int lane = t & 63, w = t >> 6;
        float am[8], a4[8];
        #pragma unroll
        for(int j=0;j<8;j++) am[j] = atta[lane*8+j];
        #pragma unroll
        for(int j=0;j<8;j++) a4[j] = (lane<16) ? atta[512+lane*8+j] : 0.f;

        int e0 = lb*16 + w*4;
        int srcs[4], dsts[4];
        #pragma unroll
        for(int i=0;i<4;i++) edge_sd(e0+i, edges, &srcs[i], &dsts[i]);
        #pragma unroll
        for(int i=0;i<4;i++){
            const unsigned short* xls = &xl[(size_t)srcs[i]*HC];
            const unsigned short* xrd = &xr[(size_t)dsts[i]*HC];
            uint4 ul = *(const uint4*)&xls[lane*8];
            uint4 ur = *(const uint4*)&xrd[lane*8];
            uint4 tl = make_uint4(0,0,0,0), tr = make_uint4(0,0,0,0);
            if(lane < 16){
                tl = *(const uint4*)&xls[512+lane*8];
                tr = *(const uint4*)&xrd[512+lane*8];
            }
            float pm = 0.f, p4 = 0.f;
            {
                unsigned pl[4] = {ul.x,ul.y,ul.z,ul.w};
                unsigned pr[4] = {ur.x,ur.y,ur.z,ur.w};
                #pragma unroll
                for(int q=0;q<4;q++){
                    float s0 = bf2f((unsigned short)(pl[q]&0xFFFFu)) + bf2f((unsigned short)(pr[q]&0xFFFFu));
                    float s1 = bf2f((unsigned short)(pl[q]>>16))     + bf2f((unsigned short)(pr[q]>>16));
                    s0 = s0 > 0.f ? s0 : NEG_SLOPE*s0;
                    s1 = s1 > 0.f ? s1 : NEG_SLOPE*s1;
                    pm = fmaf(s0, am[2*q],   pm);
                    pm = fmaf(s1, am[2*q+1], pm);
                }
            }
            {
                unsigned ql[4] = {tl.x,tl.y,tl.z,tl.w};
                unsigned qr[4] = {tr.x,tr.y,tr.z,tr.w};
                #pragma unroll
                for(int q=0;q<4;q++){
                    float s0 = bf2f((unsigned short)(ql[q]&0xFFFFu)) + bf2f((unsigned short)(qr[q]&0xFFFFu));
                    float s1 = bf2f((unsigned short)(ql[q]>>16))     + bf2f((unsigned short)(qr[q]>>16));
                    s0 = s0 > 0.f ? s0 : NEG_SLOPE*s0;
                    s1 = s1 > 0.f ? s1 : NEG_SLOPE*s1;
                    p4 = fmaf(s0, a4[2*q],   p4);
                    p4 = fmaf(s1, a4[2*q+1], p4);
                }
            }
            #pragma unroll
            for(int off=1; off<16; off<<=1){
                pm += __shfl_xor(pm, off);
                p4 += __shfl_xor(p4, off);
            }
            if((lane & 15) == 0){
                int hh = lane >> 4;
                float p = __expf(pm);
                pbuf[(size_t)(e0+i)*HEADS + hh] = p;
                atomicAdd(&segsum[dsts[i]*HEADS + hh], p);
            }
            if(lane == 8){
                float p = __expf(p4);
                pbuf[(size_t)(e0+i)*HEADS + 4] = p;
                atomicAdd(&segsum[dsts[i]*HEADS + 4], p);
            }
        }
    } else {
        int bb = blockIdx.x - 5000;
        int b = bb >> 5, ks = bb & 31;
        int k0 = ks*128;
        if(t < 128) sC[t] = c2[(size_t)b*4096 + k0 + t];
        __syncthreads();
        int j = t & 127, sub = t >> 7;
        const float* wp = &Wc[(size_t)(k0 + sub*64)*H_ + j];
        const float* cp = &sC[sub*64];
        float a0=0.f, a1=0.f, a2=0.f, a3=0.f;
        #pragma unroll
        for(int kk=0; kk<64; kk+=4){
            a0 = fmaf(cp[kk+0], wp[(size_t)(kk+0)*H_], a0);
            a1 = fmaf(cp[kk+1], wp[(size_t)(kk+1)*H_], a1);
            a2 = fmaf(cp[kk+2], wp[(size_t)(kk+2)*H_], a2);
            a3 = fmaf(cp[kk+3], wp[(size_t)(kk+3)*H_], a3);
        }
        atomicAdd(&tacc[b*H_+j], (a0+a1)+(a2+a3));
    }
}

// ---------------- K5: alpha = p/segsum + wave-cooperative ego accumulation ----------
__global__ void k_alpha(const float* __restrict__ pbuf, const float* __restrict__ segsum,
                        const int* __restrict__ edges, const unsigned short* __restrict__ xl,
                        float* __restrict__ out_alpha, float* __restrict__ node_out){
    int idx = blockIdx.x*256 + threadIdx.x;
    int lane = threadIdx.x & 63;
    bool valid = idx < ETOT*HEADS;
    int e = 0, hh = 0, src = 0, dst = 0;
    float a = 0.f;
    bool ego = false;
    if(valid){
        e = idx / HEADS; hh = idx - e*HEADS;
        edge_sd(e, edges, &src, &dst);
        a = pbuf[idx] / segsum[dst*HEADS + hh];
        out_alpha[idx] = a;
        ego = (dst % N_) == 0;
    }
    unsigned long long m = __ballot(ego);
    while(m){
        int l = __ffsll((unsigned long long)m) - 1;
        m &= (m - 1);
        float aa = __shfl(a, l);
        int ss = __shfl(src, l), dd = __shfl(dst, l), hq = __shfl(hh, l);
        int b = dd / N_;
        unsigned u = *(const unsigned*)&xl[(size_t)ss*HC + hq*H_ + lane*2];
        float* no = &node_out[b*HC + hq*H_ + lane*2];
        atomicAdd(no,     aa * bf2f((unsigned short)(u & 0xFFFFu)));
        atomicAdd(no + 1, aa * bf2f((unsigned short)(u >> 16)));
    }
}

// ---------------- K6: head, 16 blocks (one per sample) ----------------
__global__ __launch_bounds__(256) void k_head(const float* __restrict__ node_out,
        const float* __restrict__ gat_bias, const float* __restrict__ tacc,
        const float* __restrict__ bc, const float* __restrict__ phase,
        const float* __restrict__ Wp, const float* __restrict__ bp,
        const float* __restrict__ Wh, const float* __restrict__ bh,
        const float* __restrict__ Wo, const float* __restrict__ bo,
        const float* __restrict__ Wa, const float* __restrict__ ba,
        float* __restrict__ out){
    __shared__ float sF[268];
    __shared__ float sHid[128];
    int t = threadIdx.x;
    int b = blockIdx.x;
    if(t < 128){
        float s=0.f;
        #pragma unroll
        for(int hh=0;hh<HEADS;hh++) s += node_out[b*HC + hh*H_ + t];
        sF[t] = s*(1.0f/HEADS) + gat_bias[t];
    } else {
        int c = t - 128;
        sF[128+c] = fmaxf(tacc[b*H_ + c] + bc[c], 0.f);
    }
    if(t < P_){
        float s=bp[t];
        #pragma unroll
        for(int q=0;q<P_;q++) s = fmaf(phase[b*P_+q], Wp[q*P_+t], s);
        sF[256+t] = fmaxf(s, 0.f);
    }
    __syncthreads();
    if(t < 128){
        float s=bh[t];
        for(int k=0;k<2*H_+P_;k++) s = fmaf(sF[k], Wh[k*H_+t], s);
        sHid[t]=fmaxf(s,0.f);
    }
    __syncthreads();
    if(t < A_){
        float v=bo[0], ad=ba[t];
        for(int k=0;k<H_;k++){ float hv=sHid[k]; v = fmaf(hv,Wo[k],v); ad = fmaf(hv,Wa[k*A_+t],ad); }
        float m = ad;
        m += __shfl_xor(m,1); m += __shfl_xor(m,2); m += __shfl_xor(m,4);
        m *= 0.125f;
        out[b*A_+t] = v + ad - m;
    }
}

extern "C" void kernel_launch(void* const* d_in, const int* in_sizes, int n_in,
                              void* d_out, int out_size, void* d_ws, size_t ws_size,
                              hipStream_t stream) {
    (void)in_sizes; (void)n_in; (void)out_size; (void)ws_size;
    const float* obs      = (const float*)d_in[0];
    const float* phase    = (const float*)d_in[1];
    const float* obs_map  = (const float*)d_in[2];
    const int*   edges    = (const int*)  d_in[3];
    const float* W_nbrs   = (const float*)d_in[5];
    const float* b_nbrs   = (const float*)d_in[6];
    const float* W_ih     = (const float*)d_in[7];
    const float* W_hh     = (const float*)d_in[8];
    const float* b_ih     = (const float*)d_in[9];
    const float* b_hh     = (const float*)d_in[10];
    const float* Wl       = (const float*)d_in[11];
    const float* Wr       = (const float*)d_in[12];
    const float* att_a    = (const float*)d_in[13];
    const float* gat_bias = (const float*)d_in[14];
    const float* conv1_w  = (const float*)d_in[15];
    const float* conv1_b  = (const float*)d_in[16];
    const float* conv2_w  = (const float*)d_in[17];
    const float* conv2_b  = (const float*)d_in[18];
    const float* Wc       = (const float*)d_in[19];
    const float* bc       = (const float*)d_in[20];
    const float* Wp       = (const float*)d_in[21];
    const float* bp       = (const float*)d_in[22];
    const float* Wh       = (const float*)d_in[23];
    const float* bh       = (const float*)d_in[24];
    const float* Wo       = (const float*)d_in[25];
    const float* bo       = (const float*)d_in[26];
    const float* Wa       = (const float*)d_in[27];
    const float* ba       = (const float*)d_in[28];

    float* out = (float*)d_out;                 // [0,128): out ; [128,400128): alpha
    float* w   = (float*)d_ws;

    size_t off = 0;
    unsigned short* xl   = (unsigned short*)(w + off); off += (size_t)BN_*HC/2;
    unsigned short* xr   = (unsigned short*)(w + off); off += (size_t)BN_*HC/2;
    float* pbuf   = w + off; off += (size_t)ETOT*HEADS;
    float* segsum = w + off; off += (size_t)BN_*HEADS;
    float* nodeo  = w + off; off += (size_t)B_*HC;
    float* c1     = w + off; off += (size_t)16*32*16*16;
    float* c2     = w + off; off += (size_t)16*64*8*8;
    float* tacc   = w + off; off += (size_t)B_*H_;
    unsigned short* Wihb = (unsigned short*)(w + off); off += (size_t)H_*G3/2;
    unsigned short* Whhb = (unsigned short*)(w + off); off += (size_t)H_*G3/2;
    unsigned short* WTb  = (unsigned short*)(w + off); off += (size_t)2*HC*H_/2;
    unsigned short* WnTb = (unsigned short*)(w + off); off += (size_t)H_*32/2;

    k_prep_c1<<<640 + 512, 256, 0, stream>>>(W_ih, W_hh, Wl, Wr, W_nbrs, b_nbrs,
                                             Wihb, Whhb, WTb, WnTb,
                                             segsum, nodeo, tacc,
                                             obs_map, conv1_w, conv1_b, c1);

    k_gruf<<<250, 512, 0, stream>>>(obs, WnTb, Wihb, b_ih, Whhb, b_hh, WTb, xl, xr);

    k_conv2<<<(16*64*8*8)/256, 256, 0, stream>>>(c1, conv2_w, conv2_b, c2);

    k_logits_tb<<<5000 + 512, 256, 0, stream>>>(xl, xr, edges, att_a, pbuf, segsum,
                                                c2, Wc, tacc);

    k_alpha<<<(ETOT*HEADS+255)/256, 256, 0, stream>>>(pbuf, segsum, edges, xl, out+128, nodeo);

    k_head<<<B_, 256, 0, stream>>>(nodeo, gat_bias, tacc, bc, phase,
                                   Wp, bp, Wh, bh, Wo, bo, Wa, ba, out);
}